// Round 1
// baseline (8875.732 us; speedup 1.0000x reference)
//
#include <hip/hip_runtime.h>
#include <hip/hip_bf16.h>
#include <type_traits>

#define B_ 4
#define S_ 2048
#define D_ 1024
#define H_ 16
#define DH_ 64
#define NEGV (-100000.0f)

struct __align__(8) bf4 { __hip_bfloat16 x, y, z, w; };

__device__ __forceinline__ float bf2f(unsigned short u) {
  union { unsigned int i; float f; } c;
  c.i = ((unsigned int)u) << 16;
  return c.f;
}

// Detect mask element width. int32 masks (randint 0/2) contain only words 0/1.
// Random bool bytes produce other word values in the first 16384 words w.p. ~1.
__global__ void detect_mask_kernel(const int* __restrict__ mi, int* __restrict__ flag) {
  int t = threadIdx.x;
  bool bad = false;
  for (int i = t; i < 16384; i += 64) {
    int v = mi[i];
    bad = bad || (v != 0 && v != 1);
  }
  unsigned long long any = __ballot(bad);
  if (t == 0) flag[0] = (any != 0ull) ? 1 : 0;  // 1 => byte mask, 0 => int32 mask
}

// C[M,N] = A[M,K] * Bw[N,K]^T + bias  (torch Linear). fp32 accumulate.
template <typename TA, typename TC>
__global__ __launch_bounds__(256) void gemm_bias_bt(
    const TA* __restrict__ A, const float* __restrict__ Bw,
    const float* __restrict__ bias, TC* __restrict__ C,
    int M, int N, int K) {
  constexpr int BM = 128, BN = 128, BK = 32;
  __shared__ float As[BK][BM + 4];  // [k][m], 132-float stride: 16B-aligned rows
  __shared__ float Bs[BK][BN + 4];
  const int m0 = blockIdx.x * BM;
  const int n0 = blockIdx.y * BN;
  const int t = threadIdx.x;
  const int tx = t & 15, ty = t >> 4;

  float acc[8][8];
#pragma unroll
  for (int i = 0; i < 8; ++i)
#pragma unroll
    for (int j = 0; j < 8; ++j) acc[i][j] = 0.f;

  for (int k0 = 0; k0 < K; k0 += BK) {
#pragma unroll
    for (int i = 0; i < 4; ++i) {
      int f = t + i * 256;
      int m = f >> 3, kq = f & 7;
      float4 va;
      if constexpr (std::is_same_v<TA, float>) {
        va = *(const float4*)(A + (size_t)(m0 + m) * K + k0 + kq * 4);
      } else {
        ushort4 u = *(const ushort4*)(A + (size_t)(m0 + m) * K + k0 + kq * 4);
        va.x = bf2f(u.x); va.y = bf2f(u.y); va.z = bf2f(u.z); va.w = bf2f(u.w);
      }
      As[kq * 4 + 0][m] = va.x;
      As[kq * 4 + 1][m] = va.y;
      As[kq * 4 + 2][m] = va.z;
      As[kq * 4 + 3][m] = va.w;
      float4 vb = *(const float4*)(Bw + (size_t)(n0 + m) * K + k0 + kq * 4);
      Bs[kq * 4 + 0][m] = vb.x;
      Bs[kq * 4 + 1][m] = vb.y;
      Bs[kq * 4 + 2][m] = vb.z;
      Bs[kq * 4 + 3][m] = vb.w;
    }
    __syncthreads();
#pragma unroll
    for (int k = 0; k < BK; ++k) {
      float4 a0 = *(float4*)&As[k][ty * 8];
      float4 a1 = *(float4*)&As[k][ty * 8 + 4];
      float4 b0 = *(float4*)&Bs[k][tx * 8];
      float4 b1 = *(float4*)&Bs[k][tx * 8 + 4];
      float av[8] = {a0.x, a0.y, a0.z, a0.w, a1.x, a1.y, a1.z, a1.w};
      float bv[8] = {b0.x, b0.y, b0.z, b0.w, b1.x, b1.y, b1.z, b1.w};
#pragma unroll
      for (int i = 0; i < 8; ++i)
#pragma unroll
        for (int j = 0; j < 8; ++j) acc[i][j] = fmaf(av[i], bv[j], acc[i][j]);
    }
    __syncthreads();
  }

#pragma unroll
  for (int i = 0; i < 8; ++i) {
    int gm = m0 + ty * 8 + i;
    int gn = n0 + tx * 8;
    float o[8];
#pragma unroll
    for (int j = 0; j < 8; ++j) o[j] = acc[i][j] + bias[gn + j];
    if constexpr (std::is_same_v<TC, float>) {
      *(float4*)(C + (size_t)gm * N + gn) = make_float4(o[0], o[1], o[2], o[3]);
      *(float4*)(C + (size_t)gm * N + gn + 4) = make_float4(o[4], o[5], o[6], o[7]);
    } else {
      bf4 u0, u1;
      u0.x = __float2bfloat16(o[0]); u0.y = __float2bfloat16(o[1]);
      u0.z = __float2bfloat16(o[2]); u0.w = __float2bfloat16(o[3]);
      u1.x = __float2bfloat16(o[4]); u1.y = __float2bfloat16(o[5]);
      u1.z = __float2bfloat16(o[6]); u1.w = __float2bfloat16(o[7]);
      *(bf4*)(C + (size_t)gm * N + gn) = u0;
      *(bf4*)(C + (size_t)gm * N + gn + 4) = u1;
    }
  }
}

// Flash-style fused attention. Block = 16 q-rows of one (b,h); 256 thr = 16 rows x 16.
// qh,kh fp32 [B*S, D] (head-interleaved cols), vh bf16. Output bf16 [B*S, D].
__global__ __launch_bounds__(256) void attn_fused(
    const float* __restrict__ qh, const float* __restrict__ kh,
    const __hip_bfloat16* __restrict__ vh, const void* __restrict__ maskp,
    const int* __restrict__ flag, __hip_bfloat16* __restrict__ xout) {
  constexpr int QT = 16, KT = 64;
  __shared__ float Qs[QT][DH_ + 4];
  __shared__ float Ks[KT][DH_ + 4];
  __shared__ float Vs[KT][DH_ + 4];
  __shared__ float Ps[QT][KT + 1];

  const int blk = blockIdx.x;
  const int b = blk >> 11;                 // / (H * S/QT) = /2048
  const int h = (blk >> 7) & (H_ - 1);
  const int q0 = (blk & 127) << 4;
  const int t = threadIdx.x;
  const int kk = t & 15, r = t >> 4;
  const int mode = flag[0];
  const unsigned char* mask_b = (const unsigned char*)maskp;
  const int* mask_i = (const int*)maskp;

  {
    int rr = t >> 4, cc = t & 15;
    *(float4*)&Qs[rr][cc * 4] =
        *(const float4*)(qh + (size_t)(b * S_ + q0 + rr) * D_ + h * DH_ + cc * 4);
  }
  __syncthreads();
  float4 qreg[16];
#pragma unroll
  for (int i = 0; i < 16; ++i) qreg[i] = *(float4*)&Qs[r][i * 4];

  float4 o = make_float4(0.f, 0.f, 0.f, 0.f);
  float mrow = -1e30f, lrow = 0.f;

  for (int k0 = 0; k0 < S_; k0 += KT) {
    __syncthreads();  // previous PV done before overwriting Ks/Vs
#pragma unroll
    for (int i = 0; i < 4; ++i) {
      int f = t + i * 256;
      int rr = f >> 4, cc = f & 15;
      *(float4*)&Ks[rr][cc * 4] =
          *(const float4*)(kh + (size_t)(b * S_ + k0 + rr) * D_ + h * DH_ + cc * 4);
      ushort4 u = *(const ushort4*)(vh + (size_t)(b * S_ + k0 + rr) * D_ + h * DH_ + cc * 4);
      *(float4*)&Vs[rr][cc * 4] = make_float4(bf2f(u.x), bf2f(u.y), bf2f(u.z), bf2f(u.w));
    }
    __syncthreads();

    // logits for k = kp*16 + kk
    float lg[4];
#pragma unroll
    for (int kp = 0; kp < 4; ++kp) {
      int k = kp * 16 + kk;
      float a = 0.f;
#pragma unroll
      for (int d0 = 0; d0 < 16; ++d0) {
        float4 kv = *(float4*)&Ks[k][d0 * 4];
        float4 qv = qreg[d0];
        a = fmaf(qv.x, kv.x, a);
        a = fmaf(qv.y, kv.y, a);
        a = fmaf(qv.z, kv.z, a);
        a = fmaf(qv.w, kv.w, a);
      }
      lg[kp] = a;
    }
    const int mbase = b * (S_ * S_) + (q0 + r) * S_ + k0;
    if (mode) {
#pragma unroll
      for (int kp = 0; kp < 4; ++kp)
        if (mask_b[mbase + kp * 16 + kk]) lg[kp] = NEGV;
    } else {
#pragma unroll
      for (int kp = 0; kp < 4; ++kp)
        if (mask_i[mbase + kp * 16 + kk]) lg[kp] = NEGV;
    }

    float tmax = fmaxf(fmaxf(lg[0], lg[1]), fmaxf(lg[2], lg[3]));
#pragma unroll
    for (int off = 1; off < 16; off <<= 1) tmax = fmaxf(tmax, __shfl_xor(tmax, off, 16));
    float mnew = fmaxf(mrow, tmax);
    float p[4], psum = 0.f;
#pragma unroll
    for (int kp = 0; kp < 4; ++kp) { p[kp] = __expf(lg[kp] - mnew); psum += p[kp]; }
#pragma unroll
    for (int off = 1; off < 16; off <<= 1) psum += __shfl_xor(psum, off, 16);
    float scale = __expf(mrow - mnew);
    lrow = lrow * scale + psum;
    mrow = mnew;
    o.x *= scale; o.y *= scale; o.z *= scale; o.w *= scale;

#pragma unroll
    for (int kp = 0; kp < 4; ++kp) Ps[r][kp * 16 + kk] = p[kp];
    __syncthreads();

#pragma unroll 16
    for (int k = 0; k < KT; ++k) {
      float pk = Ps[r][k];
      float4 vv = *(float4*)&Vs[k][kk * 4];
      o.x = fmaf(pk, vv.x, o.x);
      o.y = fmaf(pk, vv.y, o.y);
      o.z = fmaf(pk, vv.z, o.z);
      o.w = fmaf(pk, vv.w, o.w);
    }
  }

  float inv = 1.f / lrow;
  bf4 u;
  u.x = __float2bfloat16(o.x * inv);
  u.y = __float2bfloat16(o.y * inv);
  u.z = __float2bfloat16(o.z * inv);
  u.w = __float2bfloat16(o.w * inv);
  *(bf4*)(xout + (size_t)(b * S_ + q0 + r) * D_ + h * DH_ + kk * 4) = u;
}

extern "C" void kernel_launch(void* const* d_in, const int* in_sizes, int n_in,
                              void* d_out, int out_size, void* d_ws, size_t ws_size,
                              hipStream_t stream) {
  const float* q = (const float*)d_in[0];
  const float* k = (const float*)d_in[1];
  const float* v = (const float*)d_in[2];
  const void* mask = d_in[3];
  const float* wq_w = (const float*)d_in[4];
  const float* wq_b = (const float*)d_in[5];
  const float* wk_w = (const float*)d_in[6];
  const float* wk_b = (const float*)d_in[7];
  const float* wv_w = (const float*)d_in[8];
  const float* wv_b = (const float*)d_in[9];
  const float* wo_w = (const float*)d_in[10];
  const float* wo_b = (const float*)d_in[11];

  // Workspace layout (~96 MiB):
  // [0,256)      : mask-mode flag
  // qh fp32 32MB | kh fp32 32MB | vh bf16 16MB | xattn bf16 16MB
  char* ws = (char*)d_ws;
  int* flag = (int*)ws;
  float* qh = (float*)(ws + 256);
  float* kh = qh + (size_t)B_ * S_ * D_;
  __hip_bfloat16* vh = (__hip_bfloat16*)(kh + (size_t)B_ * S_ * D_);
  __hip_bfloat16* xo = vh + (size_t)B_ * S_ * D_;

  detect_mask_kernel<<<1, 64, 0, stream>>>((const int*)mask, flag);

  dim3 g((B_ * S_) / 128, D_ / 128);
  gemm_bias_bt<float, float><<<g, 256, 0, stream>>>(q, wq_w, wq_b, qh, B_ * S_, D_, D_);
  gemm_bias_bt<float, float><<<g, 256, 0, stream>>>(k, wk_w, wk_b, kh, B_ * S_, D_, D_);
  gemm_bias_bt<float, __hip_bfloat16><<<g, 256, 0, stream>>>(v, wv_w, wv_b, vh, B_ * S_, D_, D_);

  attn_fused<<<B_ * H_ * (S_ / 16), 256, 0, stream>>>(qh, kh, vh, mask, flag, xo);

  gemm_bias_bt<__hip_bfloat16, float><<<g, 256, 0, stream>>>(xo, wo_w, wo_b, (float*)d_out,
                                                             B_ * S_, D_, D_);
}

// Round 2
// 1210.918 us; speedup vs baseline: 7.3298x; 7.3298x over previous
//
#include <hip/hip_runtime.h>
#include <hip/hip_bf16.h>
#include <type_traits>

#define B_ 4
#define S_ 2048
#define D_ 1024
#define H_ 16
#define DH_ 64
#define NEGV (-100000.0f)

typedef __attribute__((ext_vector_type(8))) short short8;
typedef __attribute__((ext_vector_type(4))) float f32x4;
typedef unsigned short us;

struct __align__(8) bf4 { us x, y, z, w; };

__device__ __forceinline__ float bf2f(us u) {
  union { unsigned int i; float f; } c;
  c.i = ((unsigned int)u) << 16;
  return c.f;
}
// round-to-nearest-even f32 -> bf16 (matches __float2bfloat16 for normals)
__device__ __forceinline__ us f2bfu(float f) {
  union { float f; unsigned int i; } c;
  c.f = f;
  unsigned int r = (c.i + 0x7fffu + ((c.i >> 16) & 1u)) >> 16;
  return (us)r;
}
__device__ __forceinline__ float bfhi_f(float f) {  // value of bf16(f) as float
  return bf2f(f2bfu(f));
}

// ---------------- mask dtype detection --------------------------------------
__global__ void detect_mask_kernel(const int* __restrict__ mi, int* __restrict__ flag) {
  int t = threadIdx.x;
  bool bad = false;
  for (int i = t; i < 16384; i += 64) {
    int v = mi[i];
    bad = bad || (v != 0 && v != 1);
  }
  unsigned long long any = __ballot(bad);
  if (t == 0) flag[0] = (any != 0ull) ? 1 : 0;  // 1 => byte mask, 0 => int32 mask
}

// ---------------- bit-pack the mask (both dtypes) ---------------------------
__global__ __launch_bounds__(256) void pack_mask(const void* __restrict__ maskp,
                                                 const int* __restrict__ flag,
                                                 unsigned* __restrict__ pk) {
  int w = blockIdx.x * 256 + threadIdx.x;  // word index over B*S*S/32
  unsigned bits = 0;
  if (flag[0]) {
    const uint4* p = (const uint4*)((const unsigned char*)maskp + (size_t)w * 32);
#pragma unroll
    for (int q = 0; q < 2; ++q) {
      uint4 v = p[q];
      unsigned vv[4] = {v.x, v.y, v.z, v.w};
#pragma unroll
      for (int e = 0; e < 4; ++e) {
        unsigned byte4 = vv[e];
#pragma unroll
        for (int bb = 0; bb < 4; ++bb)
          bits |= (unsigned)(((byte4 >> (8 * bb)) & 0xffu) != 0) << (q * 16 + e * 4 + bb);
      }
    }
  } else {
    const uint4* p = (const uint4*)((const int*)maskp + (size_t)w * 32);
#pragma unroll
    for (int q = 0; q < 8; ++q) {
      uint4 v = p[q];
      bits |= (unsigned)(v.x != 0) << (q * 4 + 0);
      bits |= (unsigned)(v.y != 0) << (q * 4 + 1);
      bits |= (unsigned)(v.z != 0) << (q * 4 + 2);
      bits |= (unsigned)(v.w != 0) << (q * 4 + 3);
    }
  }
  pk[w] = bits;
}

// ---------------- GEMM: C = A * Bw^T + bias ---------------------------------
// OMODE 0: fp32 [M][N] out.  OMODE 1: hi/lo bf16 head-split [b][h][s][64].
// OMODE 2: bf16 head-split [b][h][s][64].
template <typename TA, int OMODE>
__global__ __launch_bounds__(256) void gemm_bias_bt(
    const TA* __restrict__ A, const float* __restrict__ Bw,
    const float* __restrict__ bias, void* __restrict__ Cp, void* __restrict__ C2p,
    int M, int N, int K) {
  constexpr int BM = 128, BN = 128, BK = 32;
  __shared__ float As[BK][BM + 4];
  __shared__ float Bs[BK][BN + 4];
  const int m0 = blockIdx.x * BM;
  const int n0 = blockIdx.y * BN;
  const int t = threadIdx.x;
  const int tx = t & 15, ty = t >> 4;

  float acc[8][8];
#pragma unroll
  for (int i = 0; i < 8; ++i)
#pragma unroll
    for (int j = 0; j < 8; ++j) acc[i][j] = 0.f;

  for (int k0 = 0; k0 < K; k0 += BK) {
#pragma unroll
    for (int i = 0; i < 4; ++i) {
      int f = t + i * 256;
      int m = f >> 3, kq = f & 7;
      float4 va;
      if constexpr (std::is_same_v<TA, float>) {
        va = *(const float4*)(A + (size_t)(m0 + m) * K + k0 + kq * 4);
      } else {
        ushort4 u = *(const ushort4*)(A + (size_t)(m0 + m) * K + k0 + kq * 4);
        va.x = bf2f(u.x); va.y = bf2f(u.y); va.z = bf2f(u.z); va.w = bf2f(u.w);
      }
      As[kq * 4 + 0][m] = va.x;
      As[kq * 4 + 1][m] = va.y;
      As[kq * 4 + 2][m] = va.z;
      As[kq * 4 + 3][m] = va.w;
      float4 vb = *(const float4*)(Bw + (size_t)(n0 + m) * K + k0 + kq * 4);
      Bs[kq * 4 + 0][m] = vb.x;
      Bs[kq * 4 + 1][m] = vb.y;
      Bs[kq * 4 + 2][m] = vb.z;
      Bs[kq * 4 + 3][m] = vb.w;
    }
    __syncthreads();
#pragma unroll
    for (int k = 0; k < BK; ++k) {
      float4 a0 = *(float4*)&As[k][ty * 8];
      float4 a1 = *(float4*)&As[k][ty * 8 + 4];
      float4 b0 = *(float4*)&Bs[k][tx * 8];
      float4 b1 = *(float4*)&Bs[k][tx * 8 + 4];
      float av[8] = {a0.x, a0.y, a0.z, a0.w, a1.x, a1.y, a1.z, a1.w};
      float bv[8] = {b0.x, b0.y, b0.z, b0.w, b1.x, b1.y, b1.z, b1.w};
#pragma unroll
      for (int i = 0; i < 8; ++i)
#pragma unroll
        for (int j = 0; j < 8; ++j) acc[i][j] = fmaf(av[i], bv[j], acc[i][j]);
    }
    __syncthreads();
  }

#pragma unroll
  for (int i = 0; i < 8; ++i) {
    int gm = m0 + ty * 8 + i;
    int gn = n0 + tx * 8;
    float o[8];
#pragma unroll
    for (int j = 0; j < 8; ++j) o[j] = acc[i][j] + bias[gn + j];
    if constexpr (OMODE == 0) {
      float* C = (float*)Cp;
      *(float4*)(C + (size_t)gm * N + gn) = make_float4(o[0], o[1], o[2], o[3]);
      *(float4*)(C + (size_t)gm * N + gn + 4) = make_float4(o[4], o[5], o[6], o[7]);
    } else {
      int b = gm >> 11, s = gm & (S_ - 1);
      int hh = gn >> 6, d0 = gn & 63;
      size_t base = (((size_t)(b * H_ + hh) << 11) + s) * 64 + d0;
      if constexpr (OMODE == 1) {
        us uh[8], ul[8];
#pragma unroll
        for (int j = 0; j < 8; ++j) {
          us h = f2bfu(o[j]);
          uh[j] = h;
          ul[j] = f2bfu(o[j] - bf2f(h));
        }
        *(uint4*)((us*)Cp + base) = *(uint4*)uh;
        *(uint4*)((us*)C2p + base) = *(uint4*)ul;
      } else {
        us u[8];
#pragma unroll
        for (int j = 0; j < 8; ++j) u[j] = f2bfu(o[j]);
        *(uint4*)((us*)Cp + base) = *(uint4*)u;
      }
    }
  }
}

// ---------------- transpose per-head V: [bh][s][64] -> [bh][d][S] -----------
__global__ __launch_bounds__(256) void transpose_v(const us* __restrict__ vh,
                                                   us* __restrict__ vt) {
  __shared__ us Ts[64][72];  // 144B row stride: 16B-aligned
  int blk = blockIdx.x;  // bh*32 + stile
  int bh = blk >> 5, s0 = (blk & 31) << 6;
  int t = threadIdx.x;
#pragma unroll
  for (int p = 0; p < 2; ++p) {
    int c = t + p * 256;
    int rs = c >> 3, c8 = c & 7;
    *(uint4*)&Ts[rs][c8 * 8] = *(const uint4*)(vh + ((size_t)bh * S_ + s0 + rs) * 64 + c8 * 8);
  }
  __syncthreads();
#pragma unroll
  for (int p = 0; p < 2; ++p) {
    int c = t + p * 256;
    int rd = c >> 3, s8 = c & 7;
    union { us u[8]; uint4 v; } tmp;
#pragma unroll
    for (int e = 0; e < 8; ++e) tmp.u[e] = Ts[s8 * 8 + e][rd];
    *(uint4*)(vt + ((size_t)bh * 64 + rd) * S_ + s0 + s8 * 8) = tmp.v;
  }
}

// ---------------- MFMA flash attention --------------------------------------
// Block: 512 thr (8 waves), 128 q-rows of one (b,h). KT=64 keys/iter.
// QK^T in split precision: Qhi*Khi + Qhi*Klo + Qlo*Khi (fp32-grade logits).
__device__ __forceinline__ int swz(int row, int bc) {
  return (row << 7) + (bc ^ ((row & 7) << 4));
}

__global__ __launch_bounds__(512) void attn_mfma(
    const us* __restrict__ qhi, const us* __restrict__ qlo,
    const us* __restrict__ khi, const us* __restrict__ klo,
    const us* __restrict__ vt, const unsigned* __restrict__ pk,
    us* __restrict__ xout) {
  __shared__ __align__(16) char KHs[8192];   // [64 k][64 d] bf16, XOR-swizzled
  __shared__ __align__(16) char KLs[8192];
  __shared__ __align__(16) char VTs[8192];   // [64 d][64 k]
  __shared__ __align__(16) char Ps[16384];   // [128 q][64 k]

  const int blk = blockIdx.x;
  const int bh = blk >> 4;          // / (S/128)
  const int q0 = (blk & 15) << 7;
  const int b = bh >> 4, h = bh & (H_ - 1);
  const int t = threadIdx.x;
  const int w = t >> 6, l = t & 63;
  const int l15 = l & 15, l4 = l >> 4;

  // Q fragments, resident all kernel: rows q0+16w+(l&15), d = l4*8 + {0..7} (+32c)
  short8 qfh[2], qfl[2];
  {
    const size_t qbase = ((size_t)bh * S_ + q0 + 16 * w + l15) * 64 + l4 * 8;
    qfh[0] = *(const short8*)(qhi + qbase);
    qfh[1] = *(const short8*)(qhi + qbase + 32);
    qfl[0] = *(const short8*)(qlo + qbase);
    qfl[1] = *(const short8*)(qlo + qbase + 32);
  }

  f32x4 accO[4];
#pragma unroll
  for (int jd = 0; jd < 4; ++jd) accO[jd] = (f32x4){0.f, 0.f, 0.f, 0.f};
  float m_i[4], l_i[4];
#pragma unroll
  for (int i = 0; i < 4; ++i) { m_i[i] = -1e30f; l_i[i] = 0.f; }

  const int srow = t >> 3, sc8 = t & 7;          // staging: row, 16B-chunk
  const size_t kgbase = ((size_t)bh * S_ + srow) * 64 + sc8 * 8;
  const size_t vgbase = ((size_t)bh * 64 + srow) * S_ + sc8 * 8;
  const int swoff = swz(srow, sc8 * 16);

  for (int k0 = 0; k0 < S_; k0 += 64) {
    // mask bits for this tile (rows (l4*4+i), cols 0..63 of tile)
    uint2 mw[4];
    {
      const unsigned* pb = pk + ((size_t)b * S_ + q0 + 16 * w + (l4 << 2)) * (S_ / 32) + (k0 >> 5);
#pragma unroll
      for (int i = 0; i < 4; ++i) mw[i] = *(const uint2*)(pb + (size_t)i * (S_ / 32));
    }
    __syncthreads();  // previous iter's LDS reads complete
    *(uint4*)(KHs + swoff) = *(const uint4*)(khi + kgbase + (size_t)k0 * 64);
    *(uint4*)(KLs + swoff) = *(const uint4*)(klo + kgbase + (size_t)k0 * 64);
    *(uint4*)(VTs + swoff) = *(const uint4*)(vt + vgbase + k0);
    __syncthreads();

    // ---- QK^T: S-tile rows 16w..16w+16, cols 64 keys ----
    f32x4 sj[4];
#pragma unroll
    for (int j = 0; j < 4; ++j) {
      f32x4 s = {0.f, 0.f, 0.f, 0.f};
#pragma unroll
      for (int c = 0; c < 2; ++c) {
        short8 kf = *(const short8*)(KHs + swz(l15 + 16 * j, l4 * 16 + 64 * c));
        short8 lf = *(const short8*)(KLs + swz(l15 + 16 * j, l4 * 16 + 64 * c));
        s = __builtin_amdgcn_mfma_f32_16x16x32_bf16(qfh[c], kf, s, 0, 0, 0);
        s = __builtin_amdgcn_mfma_f32_16x16x32_bf16(qfh[c], lf, s, 0, 0, 0);
        s = __builtin_amdgcn_mfma_f32_16x16x32_bf16(qfl[c], kf, s, 0, 0, 0);
      }
      sj[j] = s;
    }
    // ---- mask ----
#pragma unroll
    for (int j = 0; j < 4; ++j) {
#pragma unroll
      for (int i = 0; i < 4; ++i) {
        unsigned bits = (j < 2) ? mw[i].x : mw[i].y;
        int sh = (l15 + 16 * j) & 31;
        if ((bits >> sh) & 1u) sj[j][i] = NEGV;
      }
    }
    // ---- online softmax (rows live in reg i across 16-lane groups) ----
#pragma unroll
    for (int i = 0; i < 4; ++i) {
      float tmax = fmaxf(fmaxf(sj[0][i], sj[1][i]), fmaxf(sj[2][i], sj[3][i]));
#pragma unroll
      for (int off = 1; off < 16; off <<= 1) tmax = fmaxf(tmax, __shfl_xor(tmax, off));
      float mnew = fmaxf(m_i[i], tmax);
      float scl = __expf(m_i[i] - mnew);
      float psum = 0.f;
      int prow = 16 * w + l4 * 4 + i;
#pragma unroll
      for (int j = 0; j < 4; ++j) {
        float p = __expf(sj[j][i] - mnew);
        psum += p;
        *(us*)(Ps + swz(prow, (l15 + 16 * j) * 2)) = f2bfu(p);
      }
#pragma unroll
      for (int off = 1; off < 16; off <<= 1) psum += __shfl_xor(psum, off);
      l_i[i] = l_i[i] * scl + psum;
      m_i[i] = mnew;
#pragma unroll
      for (int jd = 0; jd < 4; ++jd) accO[jd][i] *= scl;
    }
    // in-wave LDS ordering: P writes must land before A-frag reads
    asm volatile("s_waitcnt lgkmcnt(0)" ::: "memory");
    __builtin_amdgcn_sched_barrier(0);
    // ---- PV ----
#pragma unroll
    for (int kc = 0; kc < 2; ++kc) {
      short8 pa = *(const short8*)(Ps + swz(16 * w + l15, l4 * 16 + 64 * kc));
#pragma unroll
      for (int jd = 0; jd < 4; ++jd) {
        short8 vb = *(const short8*)(VTs + swz(l15 + 16 * jd, l4 * 16 + 64 * kc));
        accO[jd] = __builtin_amdgcn_mfma_f32_16x16x32_bf16(pa, vb, accO[jd], 0, 0, 0);
      }
    }
  }

  // epilogue: O /= l, write bf16 [b][s][h*64+d]
#pragma unroll
  for (int i = 0; i < 4; ++i) {
    float inv = 1.f / l_i[i];
    int row = q0 + 16 * w + l4 * 4 + i;
    size_t obase = ((size_t)b * S_ + row) * D_ + h * 64 + l15;
#pragma unroll
    for (int jd = 0; jd < 4; ++jd) xout[obase + 16 * jd] = f2bfu(accO[jd][i] * inv);
  }
}

extern "C" void kernel_launch(void* const* d_in, const int* in_sizes, int n_in,
                              void* d_out, int out_size, void* d_ws, size_t ws_size,
                              hipStream_t stream) {
  const float* q = (const float*)d_in[0];
  const float* k = (const float*)d_in[1];
  const float* v = (const float*)d_in[2];
  const void* mask = d_in[3];
  const float* wq_w = (const float*)d_in[4];
  const float* wq_b = (const float*)d_in[5];
  const float* wk_w = (const float*)d_in[6];
  const float* wk_b = (const float*)d_in[7];
  const float* wv_w = (const float*)d_in[8];
  const float* wv_b = (const float*)d_in[9];
  const float* wo_w = (const float*)d_in[10];
  const float* wo_b = (const float*)d_in[11];

  // ws layout: flag(256B) | pk 2MB | qhi | qlo | khi | klo | vt | vh/xo (bf16, 16MB each)
  const size_t NE = (size_t)B_ * S_ * D_;
  char* ws = (char*)d_ws;
  int* flag = (int*)ws;
  unsigned* pk = (unsigned*)(ws + 256);
  us* qhi = (us*)(ws + 256 + (size_t)(B_ * S_ * (S_ / 32)) * 4);
  us* qlo = qhi + NE;
  us* khi = qlo + NE;
  us* klo = khi + NE;
  us* vt = klo + NE;
  us* vhxo = vt + NE;  // vh before transpose, attention output after

  detect_mask_kernel<<<1, 64, 0, stream>>>((const int*)mask, flag);
  pack_mask<<<(B_ * S_ * (S_ / 32)) / 256, 256, 0, stream>>>(mask, flag, pk);

  dim3 g((B_ * S_) / 128, D_ / 128);
  gemm_bias_bt<float, 1><<<g, 256, 0, stream>>>(q, wq_w, wq_b, qhi, qlo, B_ * S_, D_, D_);
  gemm_bias_bt<float, 1><<<g, 256, 0, stream>>>(k, wk_w, wk_b, khi, klo, B_ * S_, D_, D_);
  gemm_bias_bt<float, 2><<<g, 256, 0, stream>>>(v, wv_w, wv_b, vhxo, nullptr, B_ * S_, D_, D_);
  transpose_v<<<B_ * H_ * (S_ / 64), 256, 0, stream>>>(vhxo, vt);

  attn_mfma<<<B_ * H_ * (S_ / 128), 512, 0, stream>>>(qhi, qlo, khi, klo, vt, pk, vhxo);

  gemm_bias_bt<__hip_bfloat16, 0><<<g, 256, 0, stream>>>(
      (const __hip_bfloat16*)vhxo, wo_w, wo_b, d_out, nullptr, B_ * S_, D_, D_);
}

// Round 3
// 564.745 us; speedup vs baseline: 15.7164x; 2.1442x over previous
//
#include <hip/hip_runtime.h>
#include <hip/hip_bf16.h>
#include <type_traits>

#define B_ 4
#define S_ 2048
#define D_ 1024
#define H_ 16
#define DH_ 64
#define NEGV (-100000.0f)

typedef __attribute__((ext_vector_type(8))) short short8;
typedef __attribute__((ext_vector_type(4))) float f32x4;
typedef unsigned short us;

__device__ __forceinline__ float bf2f(us u) {
  union { unsigned int i; float f; } c;
  c.i = ((unsigned int)u) << 16;
  return c.f;
}
// round-to-nearest-even f32 -> bf16
__device__ __forceinline__ us f2bfu(float f) {
  union { float f; unsigned int i; } c;
  c.f = f;
  unsigned int r = (c.i + 0x7fffu + ((c.i >> 16) & 1u)) >> 16;
  return (us)r;
}

// ---------------- mask dtype detection --------------------------------------
__global__ void detect_mask_kernel(const int* __restrict__ mi, int* __restrict__ flag) {
  int t = threadIdx.x;
  bool bad = false;
  for (int i = t; i < 16384; i += 64) {
    int v = mi[i];
    bad = bad || (v != 0 && v != 1);
  }
  unsigned long long any = __ballot(bad);
  if (t == 0) flag[0] = (any != 0ull) ? 1 : 0;  // 1 => byte mask, 0 => int32 mask
}

// ---------------- bit-pack the mask (both dtypes) ---------------------------
__global__ __launch_bounds__(256) void pack_mask(const void* __restrict__ maskp,
                                                 const int* __restrict__ flag,
                                                 unsigned* __restrict__ pk) {
  int w = blockIdx.x * 256 + threadIdx.x;  // word index over B*S*S/32
  unsigned bits = 0;
  if (flag[0]) {
    const uint4* p = (const uint4*)((const unsigned char*)maskp + (size_t)w * 32);
#pragma unroll
    for (int q = 0; q < 2; ++q) {
      uint4 v = p[q];
      unsigned vv[4] = {v.x, v.y, v.z, v.w};
#pragma unroll
      for (int e = 0; e < 4; ++e) {
        unsigned byte4 = vv[e];
#pragma unroll
        for (int bb = 0; bb < 4; ++bb)
          bits |= (unsigned)(((byte4 >> (8 * bb)) & 0xffu) != 0) << (q * 16 + e * 4 + bb);
      }
    }
  } else {
    const uint4* p = (const uint4*)((const int*)maskp + (size_t)w * 32);
#pragma unroll
    for (int q = 0; q < 8; ++q) {
      uint4 v = p[q];
      bits |= (unsigned)(v.x != 0) << (q * 4 + 0);
      bits |= (unsigned)(v.y != 0) << (q * 4 + 1);
      bits |= (unsigned)(v.z != 0) << (q * 4 + 2);
      bits |= (unsigned)(v.w != 0) << (q * 4 + 3);
    }
  }
  pk[w] = bits;
}

// ---------------- f32 -> bf16 convert / hi-lo split -------------------------
template <int MODE>  // 0: single, 1: hi+lo
__global__ __launch_bounds__(256) void cvt_split(const float* __restrict__ in,
                                                 us* __restrict__ hi, us* __restrict__ lo,
                                                 int n4) {
  int i = blockIdx.x * 256 + threadIdx.x;
  if (i >= n4) return;
  float4 v = ((const float4*)in)[i];
  float vv[4] = {v.x, v.y, v.z, v.w};
  us h[4], l[4];
#pragma unroll
  for (int e = 0; e < 4; ++e) {
    h[e] = f2bfu(vv[e]);
    if constexpr (MODE == 1) l[e] = f2bfu(vv[e] - bf2f(h[e]));
  }
  ((ushort4*)hi)[i] = *(ushort4*)h;
  if constexpr (MODE == 1) ((ushort4*)lo)[i] = *(ushort4*)l;
}

// ---------------- MFMA GEMM: C = A * W^T + bias -----------------------------
// A [M][K], W [N][K] bf16 (optionally hi/lo split pairs). fp32 accumulate.
// NSPLIT 1: C = Ah*Wh.  NSPLIT 3: C = Ah*Wh + Ah*Wl + Al*Wh.
// OMODE 0: fp32 [M][N].  OMODE 1: hi/lo bf16 head-split [b][h][s][64].
// OMODE 2: bf16 head-split.
__device__ __forceinline__ int swzb(int row, int c16) {  // byte off in [128][64]bf16 tile
  return row * 128 + ((c16 ^ (row & 7)) << 4);
}
__device__ __forceinline__ void gload16(const us* g, us* l) {
  __builtin_amdgcn_global_load_lds((const __attribute__((address_space(1))) void*)g,
                                   (__attribute__((address_space(3))) void*)l, 16, 0, 0);
}

template <int NSPLIT, int OMODE>
__global__ __launch_bounds__(256) void gemm_mfma(
    const us* __restrict__ Ahi, const us* __restrict__ Alo,
    const us* __restrict__ Whi, const us* __restrict__ Wlo,
    const float* __restrict__ bias, void* __restrict__ Cp, void* __restrict__ C2p,
    int M, int N, int K) {
  __shared__ __align__(16) us AsH[128 * 64];
  __shared__ __align__(16) us WsH[128 * 64];
  __shared__ __align__(16) us AsL[(NSPLIT == 3) ? 128 * 64 : 8];
  __shared__ __align__(16) us WsL[(NSPLIT == 3) ? 128 * 64 : 8];

  const int m0 = blockIdx.x * 128;
  const int n0 = blockIdx.y * 128;
  const int t = threadIdx.x;
  const int w = t >> 6, l = t & 63;
  const int l15 = l & 15, l4 = l >> 4;
  const int wm = w >> 1, wn = w & 1;

  // staging map: slot u = t + it*256 holds global chunk (row=u>>3, c=(u&7)^(row&7))
  int goff[4];
#pragma unroll
  for (int it = 0; it < 4; ++it) {
    int row = (t >> 3) + it * 32;
    int c = (t & 7) ^ (row & 7);
    goff[it] = row * K + c * 8;
  }
  const us* Ag = Ahi + (size_t)m0 * K;
  const us* Wg = Whi + (size_t)n0 * K;
  const us* Ag2 = (NSPLIT == 3) ? Alo + (size_t)m0 * K : nullptr;
  const us* Wg2 = (NSPLIT == 3) ? Wlo + (size_t)n0 * K : nullptr;

  f32x4 acc[4][4];
#pragma unroll
  for (int m = 0; m < 4; ++m)
#pragma unroll
    for (int n = 0; n < 4; ++n) acc[m][n] = (f32x4){0.f, 0.f, 0.f, 0.f};

  for (int k0 = 0; k0 < K; k0 += 64) {
    __syncthreads();
#pragma unroll
    for (int it = 0; it < 4; ++it) {
      us* ldst = (us*)((char*)0 + (size_t)(t + it * 256) * 16);  // byte slot (offset)
      int ub = (t + it * 256) * 8;                               // us index
      gload16(Ag + goff[it] + k0, AsH + ub);
      gload16(Wg + goff[it] + k0, WsH + ub);
      if constexpr (NSPLIT == 3) {
        gload16(Ag2 + goff[it] + k0, AsL + ub);
        gload16(Wg2 + goff[it] + k0, WsL + ub);
      }
      (void)ldst;
    }
    __syncthreads();

#pragma unroll
    for (int ks = 0; ks < 2; ++ks) {
      short8 ah[4], bh[4];
#pragma unroll
      for (int m = 0; m < 4; ++m)
        ah[m] = *(const short8*)((const char*)AsH + swzb(wm * 64 + m * 16 + l15, ks * 4 + l4));
#pragma unroll
      for (int n = 0; n < 4; ++n)
        bh[n] = *(const short8*)((const char*)WsH + swzb(wn * 64 + n * 16 + l15, ks * 4 + l4));
      if constexpr (NSPLIT == 3) {
        short8 al[4], bl[4];
#pragma unroll
        for (int m = 0; m < 4; ++m)
          al[m] = *(const short8*)((const char*)AsL + swzb(wm * 64 + m * 16 + l15, ks * 4 + l4));
#pragma unroll
        for (int n = 0; n < 4; ++n)
          bl[n] = *(const short8*)((const char*)WsL + swzb(wn * 64 + n * 16 + l15, ks * 4 + l4));
#pragma unroll
        for (int m = 0; m < 4; ++m)
#pragma unroll
          for (int n = 0; n < 4; ++n) {
            acc[m][n] = __builtin_amdgcn_mfma_f32_16x16x32_bf16(ah[m], bh[n], acc[m][n], 0, 0, 0);
            acc[m][n] = __builtin_amdgcn_mfma_f32_16x16x32_bf16(ah[m], bl[n], acc[m][n], 0, 0, 0);
            acc[m][n] = __builtin_amdgcn_mfma_f32_16x16x32_bf16(al[m], bh[n], acc[m][n], 0, 0, 0);
          }
      } else {
#pragma unroll
        for (int m = 0; m < 4; ++m)
#pragma unroll
          for (int n = 0; n < 4; ++n)
            acc[m][n] = __builtin_amdgcn_mfma_f32_16x16x32_bf16(ah[m], bh[n], acc[m][n], 0, 0, 0);
      }
    }
  }

  float bv[4];
#pragma unroll
  for (int n = 0; n < 4; ++n) bv[n] = bias[n0 + wn * 64 + n * 16 + l15];

#pragma unroll
  for (int m = 0; m < 4; ++m) {
#pragma unroll
    for (int i = 0; i < 4; ++i) {
      int gm = m0 + wm * 64 + m * 16 + l4 * 4 + i;
#pragma unroll
      for (int n = 0; n < 4; ++n) {
        int gn = n0 + wn * 64 + n * 16 + l15;
        float o = acc[m][n][i] + bv[n];
        if constexpr (OMODE == 0) {
          ((float*)Cp)[(size_t)gm * N + gn] = o;
        } else {
          int b = gm >> 11, s = gm & (S_ - 1);
          int hh = gn >> 6, d = gn & 63;
          size_t idx = (((size_t)(b * H_ + hh) << 11) + s) * 64 + d;
          us hu = f2bfu(o);
          ((us*)Cp)[idx] = hu;
          if constexpr (OMODE == 1) ((us*)C2p)[idx] = f2bfu(o - bf2f(hu));
        }
      }
    }
  }
}

// ---------------- transpose per-head V: [bh][s][64] -> [bh][d][S] -----------
__global__ __launch_bounds__(256) void transpose_v(const us* __restrict__ vh,
                                                   us* __restrict__ vt) {
  __shared__ us Ts[64][72];
  int blk = blockIdx.x;  // bh*32 + stile
  int bh = blk >> 5, s0 = (blk & 31) << 6;
  int t = threadIdx.x;
#pragma unroll
  for (int p = 0; p < 2; ++p) {
    int c = t + p * 256;
    int rs = c >> 3, c8 = c & 7;
    *(uint4*)&Ts[rs][c8 * 8] = *(const uint4*)(vh + ((size_t)bh * S_ + s0 + rs) * 64 + c8 * 8);
  }
  __syncthreads();
#pragma unroll
  for (int p = 0; p < 2; ++p) {
    int c = t + p * 256;
    int rd = c >> 3, s8 = c & 7;
    union { us u[8]; uint4 v; } tmp;
#pragma unroll
    for (int e = 0; e < 8; ++e) tmp.u[e] = Ts[s8 * 8 + e][rd];
    *(uint4*)(vt + ((size_t)bh * 64 + rd) * S_ + s0 + s8 * 8) = tmp.v;
  }
}

// ---------------- MFMA flash attention --------------------------------------
__device__ __forceinline__ int swz(int row, int bc) {
  return (row << 7) + (bc ^ ((row & 7) << 4));
}

__global__ __launch_bounds__(512) void attn_mfma(
    const us* __restrict__ qhi, const us* __restrict__ qlo,
    const us* __restrict__ khi, const us* __restrict__ klo,
    const us* __restrict__ vt, const unsigned* __restrict__ pk,
    us* __restrict__ xout) {
  __shared__ __align__(16) char KHs[8192];   // [64 k][64 d] bf16, XOR-swizzled
  __shared__ __align__(16) char KLs[8192];
  __shared__ __align__(16) char VTs[8192];   // [64 d][64 k]
  __shared__ __align__(16) char Ps[16384];   // [128 q][64 k]

  const int blk = blockIdx.x;
  const int bh = blk >> 4;
  const int q0 = (blk & 15) << 7;
  const int b = bh >> 4, h = bh & (H_ - 1);
  const int t = threadIdx.x;
  const int w = t >> 6, l = t & 63;
  const int l15 = l & 15, l4 = l >> 4;

  short8 qfh[2], qfl[2];
  {
    const size_t qbase = ((size_t)bh * S_ + q0 + 16 * w + l15) * 64 + l4 * 8;
    qfh[0] = *(const short8*)(qhi + qbase);
    qfh[1] = *(const short8*)(qhi + qbase + 32);
    qfl[0] = *(const short8*)(qlo + qbase);
    qfl[1] = *(const short8*)(qlo + qbase + 32);
  }

  f32x4 accO[4];
#pragma unroll
  for (int jd = 0; jd < 4; ++jd) accO[jd] = (f32x4){0.f, 0.f, 0.f, 0.f};
  float m_i[4], l_i[4];
#pragma unroll
  for (int i = 0; i < 4; ++i) { m_i[i] = -1e30f; l_i[i] = 0.f; }

  const int srow = t >> 3, sc8 = t & 7;
  const size_t kgbase = ((size_t)bh * S_ + srow) * 64 + sc8 * 8;
  const size_t vgbase = ((size_t)bh * 64 + srow) * S_ + sc8 * 8;
  const int swoff = swz(srow, sc8 * 16);

  for (int k0 = 0; k0 < S_; k0 += 64) {
    uint2 mw[4];
    {
      const unsigned* pb = pk + ((size_t)b * S_ + q0 + 16 * w + (l4 << 2)) * (S_ / 32) + (k0 >> 5);
#pragma unroll
      for (int i = 0; i < 4; ++i) mw[i] = *(const uint2*)(pb + (size_t)i * (S_ / 32));
    }
    __syncthreads();
    *(uint4*)(KHs + swoff) = *(const uint4*)(khi + kgbase + (size_t)k0 * 64);
    *(uint4*)(KLs + swoff) = *(const uint4*)(klo + kgbase + (size_t)k0 * 64);
    *(uint4*)(VTs + swoff) = *(const uint4*)(vt + vgbase + k0);
    __syncthreads();

    f32x4 sj[4];
#pragma unroll
    for (int j = 0; j < 4; ++j) {
      f32x4 s = {0.f, 0.f, 0.f, 0.f};
#pragma unroll
      for (int c = 0; c < 2; ++c) {
        short8 kf = *(const short8*)(KHs + swz(l15 + 16 * j, l4 * 16 + 64 * c));
        short8 lf = *(const short8*)(KLs + swz(l15 + 16 * j, l4 * 16 + 64 * c));
        s = __builtin_amdgcn_mfma_f32_16x16x32_bf16(qfh[c], kf, s, 0, 0, 0);
        s = __builtin_amdgcn_mfma_f32_16x16x32_bf16(qfh[c], lf, s, 0, 0, 0);
        s = __builtin_amdgcn_mfma_f32_16x16x32_bf16(qfl[c], kf, s, 0, 0, 0);
      }
      sj[j] = s;
    }
#pragma unroll
    for (int j = 0; j < 4; ++j) {
#pragma unroll
      for (int i = 0; i < 4; ++i) {
        unsigned bits = (j < 2) ? mw[i].x : mw[i].y;
        int sh = (l15 + 16 * j) & 31;
        if ((bits >> sh) & 1u) sj[j][i] = NEGV;
      }
    }
#pragma unroll
    for (int i = 0; i < 4; ++i) {
      float tmax = fmaxf(fmaxf(sj[0][i], sj[1][i]), fmaxf(sj[2][i], sj[3][i]));
#pragma unroll
      for (int off = 1; off < 16; off <<= 1) tmax = fmaxf(tmax, __shfl_xor(tmax, off));
      float mnew = fmaxf(m_i[i], tmax);
      float scl = __expf(m_i[i] - mnew);
      float psum = 0.f;
      int prow = 16 * w + l4 * 4 + i;
#pragma unroll
      for (int j = 0; j < 4; ++j) {
        float p = __expf(sj[j][i] - mnew);
        psum += p;
        *(us*)(Ps + swz(prow, (l15 + 16 * j) * 2)) = f2bfu(p);
      }
#pragma unroll
      for (int off = 1; off < 16; off <<= 1) psum += __shfl_xor(psum, off);
      l_i[i] = l_i[i] * scl + psum;
      m_i[i] = mnew;
#pragma unroll
      for (int jd = 0; jd < 4; ++jd) accO[jd][i] *= scl;
    }
    asm volatile("s_waitcnt lgkmcnt(0)" ::: "memory");
    __builtin_amdgcn_sched_barrier(0);
#pragma unroll
    for (int kc = 0; kc < 2; ++kc) {
      short8 pa = *(const short8*)(Ps + swz(16 * w + l15, l4 * 16 + 64 * kc));
#pragma unroll
      for (int jd = 0; jd < 4; ++jd) {
        short8 vb = *(const short8*)(VTs + swz(l15 + 16 * jd, l4 * 16 + 64 * kc));
        accO[jd] = __builtin_amdgcn_mfma_f32_16x16x32_bf16(pa, vb, accO[jd], 0, 0, 0);
      }
    }
  }

#pragma unroll
  for (int i = 0; i < 4; ++i) {
    float inv = 1.f / l_i[i];
    int row = q0 + 16 * w + l4 * 4 + i;
    size_t obase = ((size_t)b * S_ + row) * D_ + h * 64 + l15;
#pragma unroll
    for (int jd = 0; jd < 4; ++jd) xout[obase + 16 * jd] = f2bfu(accO[jd][i] * inv);
  }
}

extern "C" void kernel_launch(void* const* d_in, const int* in_sizes, int n_in,
                              void* d_out, int out_size, void* d_ws, size_t ws_size,
                              hipStream_t stream) {
  const float* q = (const float*)d_in[0];
  const float* k = (const float*)d_in[1];
  const float* v = (const float*)d_in[2];
  const void* mask = d_in[3];
  const float* wq_w = (const float*)d_in[4];
  const float* wq_b = (const float*)d_in[5];
  const float* wk_w = (const float*)d_in[6];
  const float* wk_b = (const float*)d_in[7];
  const float* wv_w = (const float*)d_in[8];
  const float* wv_b = (const float*)d_in[9];
  const float* wo_w = (const float*)d_in[10];
  const float* wo_b = (const float*)d_in[11];

  const size_t NE = (size_t)B_ * S_ * D_;   // 8M elems
  const size_t NW = (size_t)D_ * D_;        // 1M elems
  char* ws = (char*)d_ws;
  int* flag = (int*)ws;
  unsigned* pk = (unsigned*)(ws + 256);
  us* S0 = (us*)(ws + 256 + (size_t)(B_ * S_ * (S_ / 32)) * 4);
  us* S1 = S0 + NE;
  us* S2 = S1 + NE;  // qhi
  us* S3 = S2 + NE;  // qlo
  us* S4 = S3 + NE;  // khi
  us* S5 = S4 + NE;  // klo
  us* W0 = S5 + NE;
  us* W1 = W0 + NW;

  detect_mask_kernel<<<1, 64, 0, stream>>>((const int*)mask, flag);
  pack_mask<<<(B_ * S_ * (S_ / 32)) / 256, 256, 0, stream>>>(mask, flag, pk);

  dim3 g(64, 8);  // (8192/128, 1024/128)

  // Q projection (split precision)
  cvt_split<1><<<(int)(NE / 4 / 256), 256, 0, stream>>>(q, S0, S1, (int)(NE / 4));
  cvt_split<1><<<(int)(NW / 4 / 256), 256, 0, stream>>>(wq_w, W0, W1, (int)(NW / 4));
  gemm_mfma<3, 1><<<g, 256, 0, stream>>>(S0, S1, W0, W1, wq_b, S2, S3, B_ * S_, D_, D_);

  // K projection (split precision)
  cvt_split<1><<<(int)(NE / 4 / 256), 256, 0, stream>>>(k, S0, S1, (int)(NE / 4));
  cvt_split<1><<<(int)(NW / 4 / 256), 256, 0, stream>>>(wk_w, W0, W1, (int)(NW / 4));
  gemm_mfma<3, 1><<<g, 256, 0, stream>>>(S0, S1, W0, W1, wk_b, S4, S5, B_ * S_, D_, D_);

  // V projection (plain bf16) -> vh in S1, then transpose -> vt in S0
  cvt_split<0><<<(int)(NE / 4 / 256), 256, 0, stream>>>(v, S0, nullptr, (int)(NE / 4));
  cvt_split<0><<<(int)(NW / 4 / 256), 256, 0, stream>>>(wv_w, W0, nullptr, (int)(NW / 4));
  gemm_mfma<1, 2><<<g, 256, 0, stream>>>(S0, nullptr, W0, nullptr, wv_b, S1, nullptr,
                                         B_ * S_, D_, D_);
  transpose_v<<<B_ * H_ * (S_ / 64), 256, 0, stream>>>(S1, S0);

  // attention: reads S2..S5 (q/k hi/lo), vt=S0; writes xo=S1
  attn_mfma<<<B_ * H_ * (S_ / 128), 512, 0, stream>>>(S2, S3, S4, S5, S0, pk, S1);

  // output projection (plain bf16 A, bf16 W) -> fp32 d_out
  cvt_split<0><<<(int)(NW / 4 / 256), 256, 0, stream>>>(wo_w, W0, nullptr, (int)(NW / 4));
  gemm_mfma<1, 0><<<g, 256, 0, stream>>>(S1, nullptr, W0, nullptr, wo_b, d_out, nullptr,
                                         B_ * S_, D_, D_);
}

// Round 4
// 530.800 us; speedup vs baseline: 16.7214x; 1.0639x over previous
//
#include <hip/hip_runtime.h>
#include <hip/hip_bf16.h>
#include <type_traits>

#define B_ 4
#define S_ 2048
#define D_ 1024
#define H_ 16
#define DH_ 64
#define NEGV (-100000.0f)

typedef __attribute__((ext_vector_type(8))) short short8;
typedef __attribute__((ext_vector_type(4))) float f32x4;
typedef unsigned short us;

__device__ __forceinline__ float bf2f(us u) {
  union { unsigned int i; float f; } c;
  c.i = ((unsigned int)u) << 16;
  return c.f;
}
// round-to-nearest-even f32 -> bf16
__device__ __forceinline__ us f2bfu(float f) {
  union { float f; unsigned int i; } c;
  c.f = f;
  unsigned int r = (c.i + 0x7fffu + ((c.i >> 16) & 1u)) >> 16;
  return (us)r;
}

// ---------------- mask dtype detection --------------------------------------
__global__ void detect_mask_kernel(const int* __restrict__ mi, int* __restrict__ flag) {
  int t = threadIdx.x;
  bool bad = false;
  for (int i = t; i < 16384; i += 64) {
    int v = mi[i];
    bad = bad || (v != 0 && v != 1);
  }
  unsigned long long any = __ballot(bad);
  if (t == 0) flag[0] = (any != 0ull) ? 1 : 0;  // 1 => byte mask, 0 => int32 mask
}

// ---------------- bit-pack the mask (both dtypes) ---------------------------
__global__ __launch_bounds__(256) void pack_mask(const void* __restrict__ maskp,
                                                 const int* __restrict__ flag,
                                                 unsigned* __restrict__ pk) {
  int w = blockIdx.x * 256 + threadIdx.x;  // word index over B*S*S/32
  unsigned bits = 0;
  if (flag[0]) {
    const uint4* p = (const uint4*)((const unsigned char*)maskp + (size_t)w * 32);
#pragma unroll
    for (int q = 0; q < 2; ++q) {
      uint4 v = p[q];
      unsigned vv[4] = {v.x, v.y, v.z, v.w};
#pragma unroll
      for (int e = 0; e < 4; ++e) {
        unsigned byte4 = vv[e];
#pragma unroll
        for (int bb = 0; bb < 4; ++bb)
          bits |= (unsigned)(((byte4 >> (8 * bb)) & 0xffu) != 0) << (q * 16 + e * 4 + bb);
      }
    }
  } else {
    const uint4* p = (const uint4*)((const int*)maskp + (size_t)w * 32);
#pragma unroll
    for (int q = 0; q < 8; ++q) {
      uint4 v = p[q];
      bits |= (unsigned)(v.x != 0) << (q * 4 + 0);
      bits |= (unsigned)(v.y != 0) << (q * 4 + 1);
      bits |= (unsigned)(v.z != 0) << (q * 4 + 2);
      bits |= (unsigned)(v.w != 0) << (q * 4 + 3);
    }
  }
  pk[w] = bits;
}

// ---------------- f32 -> bf16 convert / hi-lo split -------------------------
template <int MODE>  // 0: single, 1: hi+lo
__global__ __launch_bounds__(256) void cvt_split(const float* __restrict__ in,
                                                 us* __restrict__ hi, us* __restrict__ lo,
                                                 int n4) {
  int i = blockIdx.x * 256 + threadIdx.x;
  if (i >= n4) return;
  float4 v = ((const float4*)in)[i];
  float vv[4] = {v.x, v.y, v.z, v.w};
  us h[4], l[4];
#pragma unroll
  for (int e = 0; e < 4; ++e) {
    h[e] = f2bfu(vv[e]);
    if constexpr (MODE == 1) l[e] = f2bfu(vv[e] - bf2f(h[e]));
  }
  ((ushort4*)hi)[i] = *(ushort4*)h;
  if constexpr (MODE == 1) ((ushort4*)lo)[i] = *(ushort4*)l;
}

__device__ __forceinline__ void gload16(const us* g, us* l) {
  __builtin_amdgcn_global_load_lds((const __attribute__((address_space(1))) void*)g,
                                   (__attribute__((address_space(3))) void*)l, 16, 0, 0);
}

// ---------------- MFMA GEMM: C = A * W^T + bias -----------------------------
// NSPLIT 3: C = Ah*Wh + Ah*Wl + Al*Wh (fp32-grade), BK=32, dbuf.
// NSPLIT 1: C = Ah*Wh, BK=64, dbuf.
// OMODE 0: fp32 [M][N].  OMODE 1: hi/lo bf16 head-split [b][h][s][64].  OMODE 2: bf16 hs.
__device__ __forceinline__ int swzb(int row, int c16) {  // [128][64] bf16 tile, XOR swz
  return row * 128 + ((c16 ^ (row & 7)) << 4);
}

template <int NSPLIT, int OMODE>
__global__ __launch_bounds__(256) void gemm_mfma(
    const us* __restrict__ Ahi, const us* __restrict__ Alo,
    const us* __restrict__ Whi, const us* __restrict__ Wlo,
    const float* __restrict__ bias, void* __restrict__ Cp, void* __restrict__ C2p,
    int M, int N, int K) {
  constexpr int BK = (NSPLIT == 3) ? 32 : 64;
  __shared__ __align__(16) us AsH[2][128 * BK];
  __shared__ __align__(16) us WsH[2][128 * BK];
  __shared__ __align__(16) us AsL[(NSPLIT == 3) ? 2 : 1][(NSPLIT == 3) ? 128 * BK : 8];
  __shared__ __align__(16) us WsL[(NSPLIT == 3) ? 2 : 1][(NSPLIT == 3) ? 128 * BK : 8];

  const int m0 = blockIdx.x * 128;
  const int n0 = blockIdx.y * 128;
  const int t = threadIdx.x;
  const int w = t >> 6, l = t & 63;
  const int l15 = l & 15, l4 = l >> 4;
  const int wm = w >> 1, wn = w & 1;

  constexpr int NST = (NSPLIT == 3) ? 2 : 4;  // 16B chunks staged per thread per array
  int goff[NST];
#pragma unroll
  for (int j = 0; j < NST; ++j) {
    int u = t + j * 256;
    if constexpr (NSPLIT == 3) {
      int r = u >> 2, p = u & 3;
      int g = (p + 4 - ((r >> 1) & 3)) & 3;   // additive-mod-4 swizzle inverse
      goff[j] = r * K + g * 8;
    } else {
      int r = u >> 3, c8 = u & 7;
      int g = c8 ^ (r & 7);                    // XOR involution
      goff[j] = r * K + g * 8;
    }
  }
  const us* Ag = Ahi + (size_t)m0 * K;
  const us* Wg = Whi + (size_t)n0 * K;
  const us* Ag2 = (NSPLIT == 3) ? Alo + (size_t)m0 * K : nullptr;
  const us* Wg2 = (NSPLIT == 3) ? Wlo + (size_t)n0 * K : nullptr;

  f32x4 acc[4][4];
#pragma unroll
  for (int m = 0; m < 4; ++m)
#pragma unroll
    for (int n = 0; n < 4; ++n) acc[m][n] = (f32x4){0.f, 0.f, 0.f, 0.f};

  auto stage = [&](int k0, int bb) {
#pragma unroll
    for (int j = 0; j < NST; ++j) {
      int u = t + j * 256;
      gload16(Ag + goff[j] + k0, &AsH[bb][u * 8]);
      gload16(Wg + goff[j] + k0, &WsH[bb][u * 8]);
      if constexpr (NSPLIT == 3) {
        gload16(Ag2 + goff[j] + k0, &AsL[bb][u * 8]);
        gload16(Wg2 + goff[j] + k0, &WsL[bb][u * 8]);
      }
    }
  };

  stage(0, 0);
  __syncthreads();
  int cur = 0;
  for (int k0 = 0; k0 < K; k0 += BK) {
    if (k0 + BK < K) stage(k0 + BK, cur ^ 1);
    if constexpr (NSPLIT == 3) {
      short8 ah[4], al[4], bh_[4], bl_[4];
#pragma unroll
      for (int m = 0; m < 4; ++m) {
        int row = wm * 64 + m * 16 + l15;
        int byo = row * 64 + ((((row >> 1) + l4) & 3) << 4);
        ah[m] = *(const short8*)((const char*)AsH[cur] + byo);
        al[m] = *(const short8*)((const char*)AsL[cur] + byo);
      }
#pragma unroll
      for (int n = 0; n < 4; ++n) {
        int row = wn * 64 + n * 16 + l15;
        int byo = row * 64 + ((((row >> 1) + l4) & 3) << 4);
        bh_[n] = *(const short8*)((const char*)WsH[cur] + byo);
        bl_[n] = *(const short8*)((const char*)WsL[cur] + byo);
      }
#pragma unroll
      for (int m = 0; m < 4; ++m)
#pragma unroll
        for (int n = 0; n < 4; ++n) {
          acc[m][n] = __builtin_amdgcn_mfma_f32_16x16x32_bf16(ah[m], bh_[n], acc[m][n], 0, 0, 0);
          acc[m][n] = __builtin_amdgcn_mfma_f32_16x16x32_bf16(ah[m], bl_[n], acc[m][n], 0, 0, 0);
          acc[m][n] = __builtin_amdgcn_mfma_f32_16x16x32_bf16(al[m], bh_[n], acc[m][n], 0, 0, 0);
        }
    } else {
#pragma unroll
      for (int ks = 0; ks < 2; ++ks) {
        short8 ah[4], bh_[4];
#pragma unroll
        for (int m = 0; m < 4; ++m)
          ah[m] = *(const short8*)((const char*)AsH[cur] + swzb(wm * 64 + m * 16 + l15, ks * 4 + l4));
#pragma unroll
        for (int n = 0; n < 4; ++n)
          bh_[n] = *(const short8*)((const char*)WsH[cur] + swzb(wn * 64 + n * 16 + l15, ks * 4 + l4));
#pragma unroll
        for (int m = 0; m < 4; ++m)
#pragma unroll
          for (int n = 0; n < 4; ++n)
            acc[m][n] = __builtin_amdgcn_mfma_f32_16x16x32_bf16(ah[m], bh_[n], acc[m][n], 0, 0, 0);
      }
    }
    __syncthreads();
    cur ^= 1;
  }

  float bv[4];
#pragma unroll
  for (int n = 0; n < 4; ++n) bv[n] = bias[n0 + wn * 64 + n * 16 + l15];

#pragma unroll
  for (int m = 0; m < 4; ++m) {
#pragma unroll
    for (int i = 0; i < 4; ++i) {
      int gm = m0 + wm * 64 + m * 16 + l4 * 4 + i;
#pragma unroll
      for (int n = 0; n < 4; ++n) {
        int gn = n0 + wn * 64 + n * 16 + l15;
        float o = acc[m][n][i] + bv[n];
        if constexpr (OMODE == 0) {
          ((float*)Cp)[(size_t)gm * N + gn] = o;
        } else {
          int b = gm >> 11, s = gm & (S_ - 1);
          int hh = gn >> 6, d = gn & 63;
          size_t idx = (((size_t)(b * H_ + hh) << 11) + s) * 64 + d;
          us hu = f2bfu(o);
          ((us*)Cp)[idx] = hu;
          if constexpr (OMODE == 1) ((us*)C2p)[idx] = f2bfu(o - bf2f(hu));
        }
      }
    }
  }
}

// ---------------- transpose per-head V: [bh][s][64] -> [bh][d][S] -----------
__global__ __launch_bounds__(256) void transpose_v(const us* __restrict__ vh,
                                                   us* __restrict__ vt) {
  __shared__ us Ts[64][72];
  int blk = blockIdx.x;  // bh*32 + stile
  int bh = blk >> 5, s0 = (blk & 31) << 6;
  int t = threadIdx.x;
#pragma unroll
  for (int p = 0; p < 2; ++p) {
    int c = t + p * 256;
    int rs = c >> 3, c8 = c & 7;
    *(uint4*)&Ts[rs][c8 * 8] = *(const uint4*)(vh + ((size_t)bh * S_ + s0 + rs) * 64 + c8 * 8);
  }
  __syncthreads();
#pragma unroll
  for (int p = 0; p < 2; ++p) {
    int c = t + p * 256;
    int rd = c >> 3, s8 = c & 7;
    union { us u[8]; uint4 v; } tmp;
#pragma unroll
    for (int e = 0; e < 8; ++e) tmp.u[e] = Ts[s8 * 8 + e][rd];
    *(uint4*)(vt + ((size_t)bh * 64 + rd) * S_ + s0 + s8 * 8) = tmp.v;
  }
}

// ---------------- MFMA flash attention (2-phase pipelined) ------------------
__device__ __forceinline__ int swz(int row, int bc) {  // [64][64] bf16 tile, XOR swz
  return (row << 7) + (bc ^ ((row & 7) << 4));
}

__global__ __launch_bounds__(512) void attn_mfma(
    const us* __restrict__ qhi, const us* __restrict__ qlo,
    const us* __restrict__ khi, const us* __restrict__ klo,
    const us* __restrict__ vt, const unsigned* __restrict__ pk,
    us* __restrict__ xout) {
  __shared__ __align__(16) us KHs[2][4096];  // [64 k][64 d] bf16, XOR-swizzled
  __shared__ __align__(16) us KLs[2][4096];
  __shared__ __align__(16) us VTs[2][4096];  // [64 d][64 k]
  __shared__ __align__(16) char Ps[16384];   // [128 q][64 k] (wave-private rows)

  // XCD-aware swizzle: 16 q-tiles of each (b,h) stay on one XCD (L2 K/V reuse)
  const int blk = ((blockIdx.x & 7) << 7) + (blockIdx.x >> 3);
  const int bh = blk >> 4;
  const int q0 = (blk & 15) << 7;
  const int b = bh >> 4, h = bh & (H_ - 1);
  const int t = threadIdx.x;
  const int w = t >> 6, l = t & 63;
  const int l15 = l & 15, l4 = l >> 4;

  short8 qfh[2], qfl[2];
  {
    const size_t qbase = ((size_t)bh * S_ + q0 + 16 * w + l15) * 64 + l4 * 8;
    qfh[0] = *(const short8*)(qhi + qbase);
    qfh[1] = *(const short8*)(qhi + qbase + 32);
    qfl[0] = *(const short8*)(qlo + qbase);
    qfl[1] = *(const short8*)(qlo + qbase + 32);
  }

  f32x4 accO[4];
#pragma unroll
  for (int jd = 0; jd < 4; ++jd) accO[jd] = (f32x4){0.f, 0.f, 0.f, 0.f};
  float m_i[4], l_p[4];  // running max; per-lane PARTIAL l (deferred row-sum)
#pragma unroll
  for (int i = 0; i < 4; ++i) { m_i[i] = -1e30f; l_p[i] = 0.f; }

  // staging: thread t stages 16B chunk t of each array; pre-swizzled global src
  const int r_st = t >> 3, c_st = (t & 7) ^ ((t >> 3) & 7);
  const us* kh_src = khi + ((size_t)bh * S_ + r_st) * 64 + c_st * 8;
  const us* kl_src = klo + ((size_t)bh * S_ + r_st) * 64 + c_st * 8;
  const us* vt_src = vt + ((size_t)bh * 64 + r_st) * S_ + c_st * 8;

  auto stage = [&](int k0, int bb) {
    gload16(kh_src + (size_t)k0 * 64, &KHs[bb][t * 8]);
    gload16(kl_src + (size_t)k0 * 64, &KLs[bb][t * 8]);
    gload16(vt_src + k0, &VTs[bb][t * 8]);
  };

  stage(0, 0);
  __syncthreads();
  int cur = 0;
  const unsigned* pb = pk + ((size_t)b * S_ + q0 + 16 * w + (l4 << 2)) * (S_ / 32);

  for (int k0 = 0; k0 < S_; k0 += 64) {
    uint2 mw[4];
#pragma unroll
    for (int i = 0; i < 4; ++i) mw[i] = *(const uint2*)(pb + (size_t)i * (S_ / 32) + (k0 >> 5));
    if (k0 + 64 < S_) stage(k0 + 64, cur ^ 1);

    const char* KH = (const char*)KHs[cur];
    const char* KL = (const char*)KLs[cur];
    const char* VT = (const char*)VTs[cur];

    // ---- QK^T (split precision) ----
    __builtin_amdgcn_s_setprio(1);
    f32x4 sj[4];
#pragma unroll
    for (int j = 0; j < 4; ++j) {
      f32x4 s = {0.f, 0.f, 0.f, 0.f};
#pragma unroll
      for (int c = 0; c < 2; ++c) {
        short8 kf = *(const short8*)(KH + swz(l15 + 16 * j, l4 * 16 + 64 * c));
        short8 lf = *(const short8*)(KL + swz(l15 + 16 * j, l4 * 16 + 64 * c));
        s = __builtin_amdgcn_mfma_f32_16x16x32_bf16(qfh[c], kf, s, 0, 0, 0);
        s = __builtin_amdgcn_mfma_f32_16x16x32_bf16(qfh[c], lf, s, 0, 0, 0);
        s = __builtin_amdgcn_mfma_f32_16x16x32_bf16(qfl[c], kf, s, 0, 0, 0);
      }
      sj[j] = s;
    }
    __builtin_amdgcn_s_setprio(0);
    // ---- mask ----
#pragma unroll
    for (int j = 0; j < 4; ++j) {
#pragma unroll
      for (int i = 0; i < 4; ++i) {
        unsigned bits = (j < 2) ? mw[i].x : mw[i].y;
        int sh = (l15 + 16 * j) & 31;
        if ((bits >> sh) & 1u) sj[j][i] = NEGV;
      }
    }
    // ---- online softmax: defer-max + deferred row-sum ----
    float mx[4];
    bool need = false;
#pragma unroll
    for (int i = 0; i < 4; ++i) {
      float tm = fmaxf(fmaxf(sj[0][i], sj[1][i]), fmaxf(sj[2][i], sj[3][i]));
#pragma unroll
      for (int off = 1; off < 16; off <<= 1) tm = fmaxf(tm, __shfl_xor(tm, off));
      mx[i] = tm;
      need = need || (tm - m_i[i] > 8.0f);
    }
    if (__any(need)) {
#pragma unroll
      for (int i = 0; i < 4; ++i) {
        float mnew = fmaxf(m_i[i], mx[i]);
        float scl = __expf(m_i[i] - mnew);
        l_p[i] *= scl;
#pragma unroll
        for (int jd = 0; jd < 4; ++jd) accO[jd][i] *= scl;
        m_i[i] = mnew;
      }
    }
#pragma unroll
    for (int i = 0; i < 4; ++i) {
      int prow = 16 * w + l4 * 4 + i;
      float p0 = __expf(sj[0][i] - m_i[i]);
      float p1 = __expf(sj[1][i] - m_i[i]);
      float p2 = __expf(sj[2][i] - m_i[i]);
      float p3 = __expf(sj[3][i] - m_i[i]);
      l_p[i] += (p0 + p1) + (p2 + p3);
      unsigned pk01, pk23;
      asm("v_cvt_pk_bf16_f32 %0, %1, %2" : "=v"(pk01) : "v"(p0), "v"(p1));
      asm("v_cvt_pk_bf16_f32 %0, %1, %2" : "=v"(pk23) : "v"(p2), "v"(p3));
      *(us*)(Ps + swz(prow, l15 * 2)) = (us)pk01;
      *(us*)(Ps + swz(prow, (l15 + 16) * 2)) = (us)(pk01 >> 16);
      *(us*)(Ps + swz(prow, (l15 + 32) * 2)) = (us)pk23;
      *(us*)(Ps + swz(prow, (l15 + 48) * 2)) = (us)(pk23 >> 16);
    }
    // in-wave ordering: P writes land before A-frag reads
    asm volatile("s_waitcnt lgkmcnt(0)" ::: "memory");
    __builtin_amdgcn_sched_barrier(0);
    // ---- PV ----
    __builtin_amdgcn_s_setprio(1);
#pragma unroll
    for (int kc = 0; kc < 2; ++kc) {
      short8 pa = *(const short8*)(Ps + swz(16 * w + l15, l4 * 16 + 64 * kc));
#pragma unroll
      for (int jd = 0; jd < 4; ++jd) {
        short8 vb = *(const short8*)(VT + swz(l15 + 16 * jd, l4 * 16 + 64 * kc));
        accO[jd] = __builtin_amdgcn_mfma_f32_16x16x32_bf16(pa, vb, accO[jd], 0, 0, 0);
      }
    }
    __builtin_amdgcn_s_setprio(0);
    __syncthreads();
    cur ^= 1;
  }

  // epilogue: finish deferred l row-sum, O /= l, write bf16 [b][s][h*64+d]
#pragma unroll
  for (int i = 0; i < 4; ++i) {
    float lr = l_p[i];
#pragma unroll
    for (int off = 1; off < 16; off <<= 1) lr += __shfl_xor(lr, off);
    float inv = 1.f / lr;
    int row = q0 + 16 * w + l4 * 4 + i;
    size_t obase = ((size_t)b * S_ + row) * D_ + h * 64 + l15;
#pragma unroll
    for (int jd = 0; jd < 4; ++jd) xout[obase + 16 * jd] = f2bfu(accO[jd][i] * inv);
  }
}

extern "C" void kernel_launch(void* const* d_in, const int* in_sizes, int n_in,
                              void* d_out, int out_size, void* d_ws, size_t ws_size,
                              hipStream_t stream) {
  const float* q = (const float*)d_in[0];
  const float* k = (const float*)d_in[1];
  const float* v = (const float*)d_in[2];
  const void* mask = d_in[3];
  const float* wq_w = (const float*)d_in[4];
  const float* wq_b = (const float*)d_in[5];
  const float* wk_w = (const float*)d_in[6];
  const float* wk_b = (const float*)d_in[7];
  const float* wv_w = (const float*)d_in[8];
  const float* wv_b = (const float*)d_in[9];
  const float* wo_w = (const float*)d_in[10];
  const float* wo_b = (const float*)d_in[11];

  const size_t NE = (size_t)B_ * S_ * D_;   // 8M elems
  const size_t NW = (size_t)D_ * D_;        // 1M elems
  char* ws = (char*)d_ws;
  int* flag = (int*)ws;
  unsigned* pk = (unsigned*)(ws + 256);
  us* S0 = (us*)(ws + 256 + (size_t)(B_ * S_ * (S_ / 32)) * 4);
  us* S1 = S0 + NE;
  us* S2 = S1 + NE;  // qhi
  us* S3 = S2 + NE;  // qlo
  us* S4 = S3 + NE;  // khi
  us* S5 = S4 + NE;  // klo
  us* W0 = S5 + NE;
  us* W1 = W0 + NW;

  detect_mask_kernel<<<1, 64, 0, stream>>>((const int*)mask, flag);
  pack_mask<<<(B_ * S_ * (S_ / 32)) / 256, 256, 0, stream>>>(mask, flag, pk);

  dim3 g(64, 8);  // (8192/128, 1024/128)

  // Q projection (split precision)
  cvt_split<1><<<(int)(NE / 4 / 256), 256, 0, stream>>>(q, S0, S1, (int)(NE / 4));
  cvt_split<1><<<(int)(NW / 4 / 256), 256, 0, stream>>>(wq_w, W0, W1, (int)(NW / 4));
  gemm_mfma<3, 1><<<g, 256, 0, stream>>>(S0, S1, W0, W1, wq_b, S2, S3, B_ * S_, D_, D_);

  // K projection (split precision)
  cvt_split<1><<<(int)(NE / 4 / 256), 256, 0, stream>>>(k, S0, S1, (int)(NE / 4));
  cvt_split<1><<<(int)(NW / 4 / 256), 256, 0, stream>>>(wk_w, W0, W1, (int)(NW / 4));
  gemm_mfma<3, 1><<<g, 256, 0, stream>>>(S0, S1, W0, W1, wk_b, S4, S5, B_ * S_, D_, D_);

  // V projection (plain bf16) -> vh in S1, then transpose -> vt in S0
  cvt_split<0><<<(int)(NE / 4 / 256), 256, 0, stream>>>(v, S0, nullptr, (int)(NE / 4));
  cvt_split<0><<<(int)(NW / 4 / 256), 256, 0, stream>>>(wv_w, W0, nullptr, (int)(NW / 4));
  gemm_mfma<1, 2><<<g, 256, 0, stream>>>(S0, nullptr, W0, nullptr, wv_b, S1, nullptr,
                                         B_ * S_, D_, D_);
  transpose_v<<<B_ * H_ * (S_ / 64), 256, 0, stream>>>(S1, S0);

  // attention: reads S2..S5 (q/k hi/lo), vt=S0; writes xo=S1
  attn_mfma<<<B_ * H_ * (S_ / 128), 512, 0, stream>>>(S2, S3, S4, S5, S0, pk, S1);

  // output projection (plain bf16 A, bf16 W) -> fp32 d_out
  cvt_split<0><<<(int)(NW / 4 / 256), 256, 0, stream>>>(wo_w, W0, nullptr, (int)(NW / 4));
  gemm_mfma<1, 0><<<g, 256, 0, stream>>>(S1, nullptr, W0, nullptr, wo_b, d_out, nullptr,
                                         B_ * S_, D_, D_);
}

// Round 5
// 404.367 us; speedup vs baseline: 21.9497x; 1.3127x over previous
//
#include <hip/hip_runtime.h>
#include <hip/hip_bf16.h>

#define B_ 4
#define S_ 2048
#define D_ 1024
#define H_ 16
#define NEGV (-100000.0f)

typedef __attribute__((ext_vector_type(8))) short short8;
typedef __attribute__((ext_vector_type(4))) float f32x4;
typedef unsigned short us;

// f32 -> f16 RTNE
__device__ __forceinline__ us f2h(float f) {
  union { _Float16 h; us u; } c;
  c.h = (_Float16)f;
  return c.u;
}

// ---------------- mask dtype detection --------------------------------------
__global__ void detect_mask_kernel(const int* __restrict__ mi, int* __restrict__ flag) {
  int t = threadIdx.x;
  bool bad = false;
  for (int i = t; i < 16384; i += 64) {
    int v = mi[i];
    bad = bad || (v != 0 && v != 1);
  }
  unsigned long long any = __ballot(bad);
  if (t == 0) flag[0] = (any != 0ull) ? 1 : 0;  // 1 => byte mask, 0 => int32 mask
}

// ---------------- bit-pack the mask (both dtypes) ---------------------------
__global__ __launch_bounds__(256) void pack_mask(const void* __restrict__ maskp,
                                                 const int* __restrict__ flag,
                                                 unsigned* __restrict__ pk) {
  int w = blockIdx.x * 256 + threadIdx.x;  // word index over B*S*S/32
  unsigned bits = 0;
  if (flag[0]) {
    const uint4* p = (const uint4*)((const unsigned char*)maskp + (size_t)w * 32);
#pragma unroll
    for (int q = 0; q < 2; ++q) {
      uint4 v = p[q];
      unsigned vv[4] = {v.x, v.y, v.z, v.w};
#pragma unroll
      for (int e = 0; e < 4; ++e) {
        unsigned byte4 = vv[e];
#pragma unroll
        for (int bb = 0; bb < 4; ++bb)
          bits |= (unsigned)(((byte4 >> (8 * bb)) & 0xffu) != 0) << (q * 16 + e * 4 + bb);
      }
    }
  } else {
    const uint4* p = (const uint4*)((const int*)maskp + (size_t)w * 32);
#pragma unroll
    for (int q = 0; q < 8; ++q) {
      uint4 v = p[q];
      bits |= (unsigned)(v.x != 0) << (q * 4 + 0);
      bits |= (unsigned)(v.y != 0) << (q * 4 + 1);
      bits |= (unsigned)(v.z != 0) << (q * 4 + 2);
      bits |= (unsigned)(v.w != 0) << (q * 4 + 3);
    }
  }
  pk[w] = bits;
}

// ---------------- f32 -> f16 converts ---------------------------------------
__global__ __launch_bounds__(256) void cvt_f16(const float* __restrict__ in,
                                               us* __restrict__ out, int n8) {
  int i = blockIdx.x * 256 + threadIdx.x;
  if (i >= n8) return;
  float4 a = ((const float4*)in)[2 * i];
  float4 b = ((const float4*)in)[2 * i + 1];
  us u[8] = {f2h(a.x), f2h(a.y), f2h(a.z), f2h(a.w),
             f2h(b.x), f2h(b.y), f2h(b.z), f2h(b.w)};
  ((uint4*)out)[i] = *(uint4*)u;
}

__global__ __launch_bounds__(256) void cvt_w4(const float* __restrict__ w0,
                                              const float* __restrict__ w1,
                                              const float* __restrict__ w2,
                                              const float* __restrict__ w3,
                                              us* __restrict__ d0, us* __restrict__ d1,
                                              us* __restrict__ d2, us* __restrict__ d3) {
  int which = blockIdx.x >> 9;             // 512 blocks per weight (1M elems / 8 / 256)
  int i = (blockIdx.x & 511) * 256 + threadIdx.x;
  const float* w = which == 0 ? w0 : which == 1 ? w1 : which == 2 ? w2 : w3;
  us* d = which == 0 ? d0 : which == 1 ? d1 : which == 2 ? d2 : d3;
  float4 a = ((const float4*)w)[2 * i];
  float4 b = ((const float4*)w)[2 * i + 1];
  us u[8] = {f2h(a.x), f2h(a.y), f2h(a.z), f2h(a.w),
             f2h(b.x), f2h(b.y), f2h(b.z), f2h(b.w)};
  ((uint4*)d)[i] = *(uint4*)u;
}

__device__ __forceinline__ void gload16(const us* g, us* l) {
  __builtin_amdgcn_global_load_lds((const __attribute__((address_space(1))) void*)g,
                                   (__attribute__((address_space(3))) void*)l, 16, 0, 0);
}

// ---------------- MFMA GEMM (fp16): C = A * W^T + bias ----------------------
// OMODE 0: fp32 [M][N].  OMODE 2: fp16 head-split [b][h][s][64].
__device__ __forceinline__ int swzb(int row, int c16) {  // [128][64] f16 tile, XOR swz
  return row * 128 + ((c16 ^ (row & 7)) << 4);
}

template <int OMODE>
__global__ __launch_bounds__(256) void gemm_mfma(
    const us* __restrict__ A, const us* __restrict__ W,
    const float* __restrict__ bias, void* __restrict__ Cp, int M, int N, int K) {
  __shared__ __align__(16) us As[2][128 * 64];
  __shared__ __align__(16) us Ws[2][128 * 64];

  const int m0 = blockIdx.x * 128;
  const int n0 = blockIdx.y * 128;
  const int t = threadIdx.x;
  const int w = t >> 6, l = t & 63;
  const int l15 = l & 15, l4 = l >> 4;
  const int wm = w >> 1, wn = w & 1;

  int goff[4];
#pragma unroll
  for (int j = 0; j < 4; ++j) {
    int u = t + j * 256;
    int r = u >> 3, c8 = u & 7;
    int g = c8 ^ (r & 7);  // XOR involution: linear LDS dest, pre-swizzled src
    goff[j] = r * K + g * 8;
  }
  const us* Ag = A + (size_t)m0 * K;
  const us* Wg = W + (size_t)n0 * K;

  f32x4 acc[4][4];
#pragma unroll
  for (int m = 0; m < 4; ++m)
#pragma unroll
    for (int n = 0; n < 4; ++n) acc[m][n] = (f32x4){0.f, 0.f, 0.f, 0.f};

  auto stage = [&](int k0, int bb) {
#pragma unroll
    for (int j = 0; j < 4; ++j) {
      int u = t + j * 256;
      gload16(Ag + goff[j] + k0, &As[bb][u * 8]);
      gload16(Wg + goff[j] + k0, &Ws[bb][u * 8]);
    }
  };

  stage(0, 0);
  __syncthreads();
  int cur = 0;
  for (int k0 = 0; k0 < K; k0 += 64) {
    if (k0 + 64 < K) stage(k0 + 64, cur ^ 1);
#pragma unroll
    for (int ks = 0; ks < 2; ++ks) {
      short8 ah[4], bh_[4];
#pragma unroll
      for (int m = 0; m < 4; ++m)
        ah[m] = *(const short8*)((const char*)As[cur] + swzb(wm * 64 + m * 16 + l15, ks * 4 + l4));
#pragma unroll
      for (int n = 0; n < 4; ++n)
        bh_[n] = *(const short8*)((const char*)Ws[cur] + swzb(wn * 64 + n * 16 + l15, ks * 4 + l4));
#pragma unroll
      for (int m = 0; m < 4; ++m)
#pragma unroll
        for (int n = 0; n < 4; ++n)
          acc[m][n] = __builtin_amdgcn_mfma_f32_16x16x32_f16(ah[m], bh_[n], acc[m][n], 0, 0, 0);
    }
    __syncthreads();
    cur ^= 1;
  }

  float bv[4];
#pragma unroll
  for (int n = 0; n < 4; ++n) bv[n] = bias[n0 + wn * 64 + n * 16 + l15];

#pragma unroll
  for (int m = 0; m < 4; ++m) {
#pragma unroll
    for (int i = 0; i < 4; ++i) {
      int gm = m0 + wm * 64 + m * 16 + l4 * 4 + i;
#pragma unroll
      for (int n = 0; n < 4; ++n) {
        int gn = n0 + wn * 64 + n * 16 + l15;
        float o = acc[m][n][i] + bv[n];
        if constexpr (OMODE == 0) {
          ((float*)Cp)[(size_t)gm * N + gn] = o;
        } else {
          int b = gm >> 11, s = gm & (S_ - 1);
          int hh = gn >> 6, d = gn & 63;
          size_t idx = (((size_t)(b * H_ + hh) << 11) + s) * 64 + d;
          ((us*)Cp)[idx] = f2h(o);
        }
      }
    }
  }
}

// ---------------- transpose per-head V: [bh][s][64] -> [bh][d][S] -----------
__global__ __launch_bounds__(256) void transpose_v(const us* __restrict__ vh,
                                                   us* __restrict__ vt) {
  __shared__ us Ts[64][72];
  int blk = blockIdx.x;  // bh*32 + stile
  int bh = blk >> 5, s0 = (blk & 31) << 6;
  int t = threadIdx.x;
#pragma unroll
  for (int p = 0; p < 2; ++p) {
    int c = t + p * 256;
    int rs = c >> 3, c8 = c & 7;
    *(uint4*)&Ts[rs][c8 * 8] = *(const uint4*)(vh + ((size_t)bh * S_ + s0 + rs) * 64 + c8 * 8);
  }
  __syncthreads();
#pragma unroll
  for (int p = 0; p < 2; ++p) {
    int c = t + p * 256;
    int rd = c >> 3, s8 = c & 7;
    union { us u[8]; uint4 v; } tmp;
#pragma unroll
    for (int e = 0; e < 8; ++e) tmp.u[e] = Ts[s8 * 8 + e][rd];
    *(uint4*)(vt + ((size_t)bh * 64 + rd) * S_ + s0 + s8 * 8) = tmp.v;
  }
}

// ---------------- MFMA flash attention (fp16, 2-phase pipelined) ------------
__device__ __forceinline__ int swz(int row, int bc) {  // [64][64] f16 tile, XOR swz
  return (row << 7) + (bc ^ ((row & 7) << 4));
}

__global__ __launch_bounds__(512) void attn_mfma(
    const us* __restrict__ qh, const us* __restrict__ kh,
    const us* __restrict__ vt, const unsigned* __restrict__ pk,
    us* __restrict__ xout) {
  __shared__ __align__(16) us Ks[2][4096];  // [64 k][64 d] f16, XOR-swizzled
  __shared__ __align__(16) us Vs[2][4096];  // [64 d][64 k]
  __shared__ __align__(16) char Ps[16384];  // [128 q][64 k] f16 (wave-private rows)

  // XCD-aware swizzle: 16 q-tiles of each (b,h) stay on one XCD (K/V L2 reuse)
  const int blk = ((blockIdx.x & 7) << 7) + (blockIdx.x >> 3);
  const int bh = blk >> 4;
  const int q0 = (blk & 15) << 7;
  const int b = bh >> 4, h = bh & (H_ - 1);
  const int t = threadIdx.x;
  const int w = t >> 6, l = t & 63;
  const int l15 = l & 15, l4 = l >> 4;

  short8 qf[2];
  {
    const size_t qbase = ((size_t)bh * S_ + q0 + 16 * w + l15) * 64 + l4 * 8;
    qf[0] = *(const short8*)(qh + qbase);
    qf[1] = *(const short8*)(qh + qbase + 32);
  }

  f32x4 accO[4];
#pragma unroll
  for (int jd = 0; jd < 4; ++jd) accO[jd] = (f32x4){0.f, 0.f, 0.f, 0.f};
  float m_i[4], l_p[4];  // running max; per-lane PARTIAL l (deferred row-sum)
#pragma unroll
  for (int i = 0; i < 4; ++i) { m_i[i] = -1e30f; l_p[i] = 0.f; }

  // staging: thread t stages 16B chunk t; pre-swizzled global src, linear LDS dest
  const int r_st = t >> 3, c_st = (t & 7) ^ ((t >> 3) & 7);
  const us* kh_src = kh + ((size_t)bh * S_ + r_st) * 64 + c_st * 8;
  const us* vt_src = vt + ((size_t)bh * 64 + r_st) * S_ + c_st * 8;

  auto stage = [&](int k0, int bb) {
    gload16(kh_src + (size_t)k0 * 64, &Ks[bb][t * 8]);
    gload16(vt_src + k0, &Vs[bb][t * 8]);
  };

  stage(0, 0);
  __syncthreads();
  int cur = 0;
  const unsigned* pb = pk + ((size_t)b * S_ + q0 + 16 * w + (l4 << 2)) * (S_ / 32);

  for (int k0 = 0; k0 < S_; k0 += 64) {
    uint2 mw[4];
#pragma unroll
    for (int i = 0; i < 4; ++i) mw[i] = *(const uint2*)(pb + (size_t)i * (S_ / 32) + (k0 >> 5));
    if (k0 + 64 < S_) stage(k0 + 64, cur ^ 1);

    const char* KT = (const char*)Ks[cur];
    const char* VT = (const char*)Vs[cur];

    // ---- QK^T ----
    __builtin_amdgcn_s_setprio(1);
    f32x4 sj[4];
#pragma unroll
    for (int j = 0; j < 4; ++j) {
      f32x4 s = {0.f, 0.f, 0.f, 0.f};
#pragma unroll
      for (int c = 0; c < 2; ++c) {
        short8 kf = *(const short8*)(KT + swz(l15 + 16 * j, l4 * 16 + 64 * c));
        s = __builtin_amdgcn_mfma_f32_16x16x32_f16(qf[c], kf, s, 0, 0, 0);
      }
      sj[j] = s;
    }
    __builtin_amdgcn_s_setprio(0);
    // ---- mask ----
#pragma unroll
    for (int j = 0; j < 4; ++j) {
#pragma unroll
      for (int i = 0; i < 4; ++i) {
        unsigned bits = (j < 2) ? mw[i].x : mw[i].y;
        int sh = (l15 + 16 * j) & 31;
        if ((bits >> sh) & 1u) sj[j][i] = NEGV;
      }
    }
    // ---- online softmax: defer-max + deferred row-sum ----
    float mx[4];
    bool need = false;
#pragma unroll
    for (int i = 0; i < 4; ++i) {
      float tm = fmaxf(fmaxf(sj[0][i], sj[1][i]), fmaxf(sj[2][i], sj[3][i]));
#pragma unroll
      for (int off = 1; off < 16; off <<= 1) tm = fmaxf(tm, __shfl_xor(tm, off));
      mx[i] = tm;
      need = need || (tm - m_i[i] > 8.0f);
    }
    if (__any(need)) {
#pragma unroll
      for (int i = 0; i < 4; ++i) {
        float mnew = fmaxf(m_i[i], mx[i]);
        float scl = __expf(m_i[i] - mnew);
        l_p[i] *= scl;
#pragma unroll
        for (int jd = 0; jd < 4; ++jd) accO[jd][i] *= scl;
        m_i[i] = mnew;
      }
    }
#pragma unroll
    for (int i = 0; i < 4; ++i) {
      int prow = 16 * w + l4 * 4 + i;
      float p0 = __expf(sj[0][i] - m_i[i]);
      float p1 = __expf(sj[1][i] - m_i[i]);
      float p2 = __expf(sj[2][i] - m_i[i]);
      float p3 = __expf(sj[3][i] - m_i[i]);
      l_p[i] += (p0 + p1) + (p2 + p3);
      unsigned pk01, pk23;
      asm("v_cvt_pkrtz_f16_f32 %0, %1, %2" : "=v"(pk01) : "v"(p0), "v"(p1));
      asm("v_cvt_pkrtz_f16_f32 %0, %1, %2" : "=v"(pk23) : "v"(p2), "v"(p3));
      *(us*)(Ps + swz(prow, l15 * 2)) = (us)pk01;
      *(us*)(Ps + swz(prow, (l15 + 16) * 2)) = (us)(pk01 >> 16);
      *(us*)(Ps + swz(prow, (l15 + 32) * 2)) = (us)pk23;
      *(us*)(Ps + swz(prow, (l15 + 48) * 2)) = (us)(pk23 >> 16);
    }
    // in-wave ordering: P writes land before A-frag reads
    asm volatile("s_waitcnt lgkmcnt(0)" ::: "memory");
    __builtin_amdgcn_sched_barrier(0);
    // ---- PV ----
    __builtin_amdgcn_s_setprio(1);
#pragma unroll
    for (int kc = 0; kc < 2; ++kc) {
      short8 pa = *(const short8*)(Ps + swz(16 * w + l15, l4 * 16 + 64 * kc));
#pragma unroll
      for (int jd = 0; jd < 4; ++jd) {
        short8 vb = *(const short8*)(VT + swz(l15 + 16 * jd, l4 * 16 + 64 * kc));
        accO[jd] = __builtin_amdgcn_mfma_f32_16x16x32_f16(pa, vb, accO[jd], 0, 0, 0);
      }
    }
    __builtin_amdgcn_s_setprio(0);
    __syncthreads();
    cur ^= 1;
  }

  // epilogue: finish deferred l row-sum, O /= l, write f16 [b][s][h*64+d]
#pragma unroll
  for (int i = 0; i < 4; ++i) {
    float lr = l_p[i];
#pragma unroll
    for (int off = 1; off < 16; off <<= 1) lr += __shfl_xor(lr, off);
    float inv = 1.f / lr;
    int row = q0 + 16 * w + l4 * 4 + i;
    size_t obase = ((size_t)b * S_ + row) * D_ + h * 64 + l15;
#pragma unroll
    for (int jd = 0; jd < 4; ++jd) xout[obase + 16 * jd] = f2h(accO[jd][i] * inv);
  }
}

extern "C" void kernel_launch(void* const* d_in, const int* in_sizes, int n_in,
                              void* d_out, int out_size, void* d_ws, size_t ws_size,
                              hipStream_t stream) {
  const float* q = (const float*)d_in[0];
  const float* k = (const float*)d_in[1];
  const float* v = (const float*)d_in[2];
  const void* mask = d_in[3];
  const float* wq_w = (const float*)d_in[4];
  const float* wq_b = (const float*)d_in[5];
  const float* wk_w = (const float*)d_in[6];
  const float* wk_b = (const float*)d_in[7];
  const float* wv_w = (const float*)d_in[8];
  const float* wv_b = (const float*)d_in[9];
  const float* wo_w = (const float*)d_in[10];
  const float* wo_b = (const float*)d_in[11];

  const size_t NE = (size_t)B_ * S_ * D_;  // 8M elems
  const size_t NW = (size_t)D_ * D_;       // 1M elems
  char* ws = (char*)d_ws;
  int* flag = (int*)ws;
  unsigned* pk = (unsigned*)(ws + 256);
  us* C0 = (us*)(ws + 256 + (size_t)(B_ * S_ * (S_ / 32)) * 4);  // cvt input / vt
  us* qh = C0 + NE;
  us* kh = qh + NE;
  us* vh = kh + NE;  // vh, later attention output
  us* W0 = vh + NE;
  us* W1 = W0 + NW;
  us* W2 = W1 + NW;
  us* W3 = W2 + NW;

  detect_mask_kernel<<<1, 64, 0, stream>>>((const int*)mask, flag);
  pack_mask<<<(B_ * S_ * (S_ / 32)) / 256, 256, 0, stream>>>(mask, flag, pk);
  cvt_w4<<<2048, 256, 0, stream>>>(wq_w, wk_w, wv_w, wo_w, W0, W1, W2, W3);

  dim3 g(64, 8);  // (8192/128, 1024/128)
  const int n8 = (int)(NE / 8);

  cvt_f16<<<n8 / 256, 256, 0, stream>>>(q, C0, n8);
  gemm_mfma<2><<<g, 256, 0, stream>>>(C0, W0, wq_b, qh, B_ * S_, D_, D_);

  cvt_f16<<<n8 / 256, 256, 0, stream>>>(k, C0, n8);
  gemm_mfma<2><<<g, 256, 0, stream>>>(C0, W1, wk_b, kh, B_ * S_, D_, D_);

  cvt_f16<<<n8 / 256, 256, 0, stream>>>(v, C0, n8);
  gemm_mfma<2><<<g, 256, 0, stream>>>(C0, W2, wv_b, vh, B_ * S_, D_, D_);

  transpose_v<<<B_ * H_ * (S_ / 64), 256, 0, stream>>>(vh, C0);  // vt in C0

  attn_mfma<<<B_ * H_ * (S_ / 128), 512, 0, stream>>>(qh, kh, C0, pk, vh);  // xo in vh

  gemm_mfma<0><<<g, 256, 0, stream>>>(vh, W3, wo_b, d_out, B_ * S_, D_, D_);
}

// Round 6
// 364.123 us; speedup vs baseline: 24.3757x; 1.1105x over previous
//
#include <hip/hip_runtime.h>
#include <hip/hip_bf16.h>

#define B_ 4
#define S_ 2048
#define D_ 1024
#define H_ 16
#define NEGV (-100000.0f)
#define L2E 1.4426950408889634f

typedef __attribute__((ext_vector_type(8))) short short8;
typedef __attribute__((ext_vector_type(4))) float f32x4;
typedef unsigned short us;
typedef unsigned long long u64;

// f32 -> f16 RTNE
__device__ __forceinline__ us f2h(float f) {
  union { _Float16 h; us u; } c;
  c.h = (_Float16)f;
  return c.u;
}
__device__ __forceinline__ float exp2a(float x) {
  float r;
  asm("v_exp_f32 %0, %1" : "=v"(r) : "v"(x));
  return r;
}

// ---------------- mask dtype detection --------------------------------------
__global__ void detect_mask_kernel(const int* __restrict__ mi, int* __restrict__ flag) {
  int t = threadIdx.x;
  bool bad = false;
  for (int i = t; i < 16384; i += 64) {
    int v = mi[i];
    bad = bad || (v != 0 && v != 1);
  }
  unsigned long long any = __ballot(bad);
  if (t == 0) flag[0] = (any != 0ull) ? 1 : 0;  // 1 => byte mask, 0 => int32 mask
}

// ---------------- bit-pack the mask (both dtypes) ---------------------------
__global__ __launch_bounds__(256) void pack_mask(const void* __restrict__ maskp,
                                                 const int* __restrict__ flag,
                                                 unsigned* __restrict__ pk) {
  int w = blockIdx.x * 256 + threadIdx.x;  // word index over B*S*S/32
  unsigned bits = 0;
  if (flag[0]) {
    const uint4* p = (const uint4*)((const unsigned char*)maskp + (size_t)w * 32);
#pragma unroll
    for (int q = 0; q < 2; ++q) {
      uint4 v = p[q];
      unsigned vv[4] = {v.x, v.y, v.z, v.w};
#pragma unroll
      for (int e = 0; e < 4; ++e) {
        unsigned byte4 = vv[e];
#pragma unroll
        for (int bb = 0; bb < 4; ++bb)
          bits |= (unsigned)(((byte4 >> (8 * bb)) & 0xffu) != 0) << (q * 16 + e * 4 + bb);
      }
    }
  } else {
    const uint4* p = (const uint4*)((const int*)maskp + (size_t)w * 32);
#pragma unroll
    for (int q = 0; q < 8; ++q) {
      uint4 v = p[q];
      bits |= (unsigned)(v.x != 0) << (q * 4 + 0);
      bits |= (unsigned)(v.y != 0) << (q * 4 + 1);
      bits |= (unsigned)(v.z != 0) << (q * 4 + 2);
      bits |= (unsigned)(v.w != 0) << (q * 4 + 3);
    }
  }
  pk[w] = bits;
}

// ---------------- f32 -> f16 converts (up to 3 tensors in one launch) -------
__global__ __launch_bounds__(256) void cvt_f16x3(const float* __restrict__ i0,
                                                 const float* __restrict__ i1,
                                                 const float* __restrict__ i2,
                                                 us* __restrict__ o0, us* __restrict__ o1,
                                                 us* __restrict__ o2) {
  int z = blockIdx.x >> 12;  // 4096 blocks per tensor (8M elems / 8 / 256)
  int i = (blockIdx.x & 4095) * 256 + threadIdx.x;
  const float* in = z == 0 ? i0 : z == 1 ? i1 : i2;
  us* out = z == 0 ? o0 : z == 1 ? o1 : o2;
  float4 a = ((const float4*)in)[2 * i];
  float4 b = ((const float4*)in)[2 * i + 1];
  us u[8] = {f2h(a.x), f2h(a.y), f2h(a.z), f2h(a.w),
             f2h(b.x), f2h(b.y), f2h(b.z), f2h(b.w)};
  ((uint4*)out)[i] = *(uint4*)u;
}

__global__ __launch_bounds__(256) void cvt_w4(const float* __restrict__ w0,
                                              const float* __restrict__ w1,
                                              const float* __restrict__ w2,
                                              const float* __restrict__ w3,
                                              us* __restrict__ d0, us* __restrict__ d1,
                                              us* __restrict__ d2, us* __restrict__ d3) {
  int which = blockIdx.x >> 9;  // 512 blocks per weight (1M elems / 8 / 256)
  int i = (blockIdx.x & 511) * 256 + threadIdx.x;
  const float* w = which == 0 ? w0 : which == 1 ? w1 : which == 2 ? w2 : w3;
  us* d = which == 0 ? d0 : which == 1 ? d1 : which == 2 ? d2 : d3;
  float4 a = ((const float4*)w)[2 * i];
  float4 b = ((const float4*)w)[2 * i + 1];
  us u[8] = {f2h(a.x), f2h(a.y), f2h(a.z), f2h(a.w),
             f2h(b.x), f2h(b.y), f2h(b.z), f2h(b.w)};
  ((uint4*)d)[i] = *(uint4*)u;
}

__device__ __forceinline__ void gload16(const us* g, us* l) {
  __builtin_amdgcn_global_load_lds((const __attribute__((address_space(1))) void*)g,
                                   (__attribute__((address_space(3))) void*)l, 16, 0, 0);
}

// ---------------- MFMA GEMM (fp16): C = A * W^T + bias, up to 3 per launch --
// OMODE 0: fp32 [M][N].  OMODE 2: fp16 head-split [b][h][s][64].
__device__ __forceinline__ int swzb(int row, int c16) {  // [128][64] f16 tile, XOR swz
  return row * 128 + ((c16 ^ (row & 7)) << 4);
}

template <int OMODE>
__global__ __launch_bounds__(256) void gemm_mfma(
    const us* __restrict__ A0, const us* __restrict__ A1, const us* __restrict__ A2,
    const us* __restrict__ Wp0, const us* __restrict__ Wp1, const us* __restrict__ Wp2,
    const float* __restrict__ b0, const float* __restrict__ b1, const float* __restrict__ b2,
    void* __restrict__ C0, void* __restrict__ C1, void* __restrict__ C2,
    int M, int N, int K) {
  __shared__ __align__(16) us As[2][128 * 64];
  __shared__ __align__(16) us Ws[2][128 * 64];

  const int z = blockIdx.z;
  const us* A = z == 0 ? A0 : z == 1 ? A1 : A2;
  const us* W = z == 0 ? Wp0 : z == 1 ? Wp1 : Wp2;
  const float* bias = z == 0 ? b0 : z == 1 ? b1 : b2;
  void* Cp = z == 0 ? C0 : z == 1 ? C1 : C2;

  const int m0 = blockIdx.x * 128;
  const int n0 = blockIdx.y * 128;
  const int t = threadIdx.x;
  const int w = t >> 6, l = t & 63;
  const int l15 = l & 15, l4 = l >> 4;
  const int wm = w >> 1, wn = w & 1;

  int goff[4];
#pragma unroll
  for (int j = 0; j < 4; ++j) {
    int u = t + j * 256;
    int r = u >> 3, c8 = u & 7;
    int g = c8 ^ (r & 7);  // XOR involution: linear LDS dest, pre-swizzled src
    goff[j] = r * K + g * 8;
  }
  const us* Ag = A + (size_t)m0 * K;
  const us* Wg = W + (size_t)n0 * K;

  f32x4 acc[4][4];
#pragma unroll
  for (int m = 0; m < 4; ++m)
#pragma unroll
    for (int n = 0; n < 4; ++n) acc[m][n] = (f32x4){0.f, 0.f, 0.f, 0.f};

  auto stage = [&](int k0, int bb) {
#pragma unroll
    for (int j = 0; j < 4; ++j) {
      int u = t + j * 256;
      gload16(Ag + goff[j] + k0, &As[bb][u * 8]);
      gload16(Wg + goff[j] + k0, &Ws[bb][u * 8]);
    }
  };

  stage(0, 0);
  __syncthreads();
  int cur = 0;
  for (int k0 = 0; k0 < K; k0 += 64) {
    if (k0 + 64 < K) stage(k0 + 64, cur ^ 1);
#pragma unroll
    for (int ks = 0; ks < 2; ++ks) {
      short8 ah[4], bh_[4];
#pragma unroll
      for (int m = 0; m < 4; ++m)
        ah[m] = *(const short8*)((const char*)As[cur] + swzb(wm * 64 + m * 16 + l15, ks * 4 + l4));
#pragma unroll
      for (int n = 0; n < 4; ++n)
        bh_[n] = *(const short8*)((const char*)Ws[cur] + swzb(wn * 64 + n * 16 + l15, ks * 4 + l4));
#pragma unroll
      for (int m = 0; m < 4; ++m)
#pragma unroll
        for (int n = 0; n < 4; ++n)
          acc[m][n] = __builtin_amdgcn_mfma_f32_16x16x32_f16(ah[m], bh_[n], acc[m][n], 0, 0, 0);
    }
    __syncthreads();
    cur ^= 1;
  }

  float bv[4];
#pragma unroll
  for (int n = 0; n < 4; ++n) bv[n] = bias[n0 + wn * 64 + n * 16 + l15];

#pragma unroll
  for (int m = 0; m < 4; ++m) {
#pragma unroll
    for (int i = 0; i < 4; ++i) {
      int gm = m0 + wm * 64 + m * 16 + l4 * 4 + i;
#pragma unroll
      for (int n = 0; n < 4; ++n) {
        int gn = n0 + wn * 64 + n * 16 + l15;
        float o = acc[m][n][i] + bv[n];
        if constexpr (OMODE == 0) {
          ((float*)Cp)[(size_t)gm * N + gn] = o;
        } else {
          int b = gm >> 11, s = gm & (S_ - 1);
          int hh = gn >> 6, d = gn & 63;
          size_t idx = (((size_t)(b * H_ + hh) << 11) + s) * 64 + d;
          ((us*)Cp)[idx] = f2h(o);
        }
      }
    }
  }
}

// ---------------- transpose per-head V: [bh][s][64] -> [bh][d][S] -----------
__global__ __launch_bounds__(256) void transpose_v(const us* __restrict__ vh,
                                                   us* __restrict__ vt) {
  __shared__ us Ts[64][72];
  int blk = blockIdx.x;  // bh*32 + stile
  int bh = blk >> 5, s0 = (blk & 31) << 6;
  int t = threadIdx.x;
#pragma unroll
  for (int p = 0; p < 2; ++p) {
    int c = t + p * 256;
    int rs = c >> 3, c8 = c & 7;
    *(uint4*)&Ts[rs][c8 * 8] = *(const uint4*)(vh + ((size_t)bh * S_ + s0 + rs) * 64 + c8 * 8);
  }
  __syncthreads();
#pragma unroll
  for (int p = 0; p < 2; ++p) {
    int c = t + p * 256;
    int rd = c >> 3, s8 = c & 7;
    union { us u[8]; uint4 v; } tmp;
#pragma unroll
    for (int e = 0; e < 8; ++e) tmp.u[e] = Ts[s8 * 8 + e][rd];
    *(uint4*)(vt + ((size_t)bh * 64 + rd) * S_ + s0 + s8 * 8) = tmp.v;
  }
}

// ---------------- MFMA flash attention (fp16, swapped-S^T, 2-phase) ---------
// S^T = mfma(K, Q): each lane owns one query (l15) and 16 keys -> lane-local
// softmax (max tree + 2 shuffles), 1 mask load, P packed as 4x ds_write_b64.
__device__ __forceinline__ int swz(int row, int bc) {  // [64][64] f16 tile, XOR swz
  return (row << 7) + (bc ^ ((row & 7) << 4));
}

__global__ __launch_bounds__(512) void attn_mfma(
    const us* __restrict__ qh, const us* __restrict__ kh,
    const us* __restrict__ vt, const unsigned* __restrict__ pk,
    us* __restrict__ xout) {
  __shared__ __align__(16) us Ks[2][4096];  // [64 k][64 d] f16, XOR-swizzled
  __shared__ __align__(16) us Vs[2][4096];  // [64 d][64 k]
  __shared__ __align__(16) char Ps[16384];  // [128 q][64 k] f16 (wave-private rows)

  // XCD-aware swizzle: 16 q-tiles of each (b,h) stay on one XCD (K/V L2 reuse)
  const int blk = ((blockIdx.x & 7) << 7) + (blockIdx.x >> 3);
  const int bh = blk >> 4;
  const int q0 = (blk & 15) << 7;
  const int b = bh >> 4, h = bh & (H_ - 1);
  const int t = threadIdx.x;
  const int w = t >> 6, l = t & 63;
  const int l15 = l & 15, l4 = l >> 4;

  short8 qf[2];
  {
    const size_t qbase = ((size_t)bh * S_ + q0 + 16 * w + l15) * 64 + l4 * 8;
    qf[0] = *(const short8*)(qh + qbase);
    qf[1] = *(const short8*)(qh + qbase + 32);
  }

  f32x4 accO[4];
#pragma unroll
  for (int jd = 0; jd < 4; ++jd) accO[jd] = (f32x4){0.f, 0.f, 0.f, 0.f};
  float m_i = -1e30f, l_p = 0.f;  // per-lane: query l15's running max / partial sum

  // staging: thread t stages 16B chunk t; pre-swizzled global src, linear LDS dest
  const int r_st = t >> 3, c_st = (t & 7) ^ ((t >> 3) & 7);
  const us* kh_src = kh + ((size_t)bh * S_ + r_st) * 64 + c_st * 8;
  const us* vt_src = vt + ((size_t)bh * 64 + r_st) * S_ + c_st * 8;

  auto stage = [&](int k0, int bb) {
    gload16(kh_src + (size_t)k0 * 64, &Ks[bb][t * 8]);
    gload16(vt_src + k0, &Vs[bb][t * 8]);
  };

  stage(0, 0);
  __syncthreads();
  int cur = 0;

  char* Pw = Ps + w * 2048;          // wave-private 16 rows
  const int prowb = l15 * 128;       // row byte offset
  const int rr7 = l15 & 7;
  const int bhalf = l4 >> 1;         // write chunk bit0
  const int wsub = (l4 & 1) * 8;     // 8B sub-slot
  const unsigned* pb = pk + ((size_t)b * S_ + q0 + 16 * w + l15) * (S_ / 32);

  for (int k0 = 0; k0 < S_; k0 += 64) {
    uint2 mw = *(const uint2*)(pb + (k0 >> 5));
    if (k0 + 64 < S_) stage(k0 + 64, cur ^ 1);

    const char* KT = (const char*)Ks[cur];
    const char* VT = (const char*)Vs[cur];

    // ---- S^T = K · Q^T : lane holds S[key = 16j+4*l4+i][q = l15] ----
    __builtin_amdgcn_s_setprio(1);
    f32x4 sj[4];
#pragma unroll
    for (int j = 0; j < 4; ++j) {
      f32x4 s = {0.f, 0.f, 0.f, 0.f};
#pragma unroll
      for (int c = 0; c < 2; ++c) {
        short8 kf = *(const short8*)(KT + swz(l15 + 16 * j, l4 * 16 + 64 * c));
        s = __builtin_amdgcn_mfma_f32_16x16x32_f16(kf, qf[c], s, 0, 0, 0);
      }
      sj[j] = s;
    }
    __builtin_amdgcn_s_setprio(0);

    // ---- mask (1 uint2, lane-local bits) + lane-local max ----
    float tm = -3e38f;
#pragma unroll
    for (int j = 0; j < 4; ++j) {
      unsigned wrd = (j < 2) ? mw.x : mw.y;
      int bb = ((j & 1) << 4) + (l4 << 2);
#pragma unroll
      for (int i = 0; i < 4; ++i) {
        float bf = (float)((wrd >> (bb + i)) & 1u);
        sj[j][i] = fmaf(bf, NEGV, sj[j][i]);
      }
      tm = fmaxf(tm, fmaxf(fmaxf(sj[j][0], sj[j][1]), fmaxf(sj[j][2], sj[j][3])));
    }
    tm = fmaxf(tm, __shfl_xor(tm, 16));
    tm = fmaxf(tm, __shfl_xor(tm, 32));

    // ---- defer-max rescale (rare, wave-uniform) ----
    if (__any(tm - m_i > 8.0f)) {
      float mnew = fmaxf(m_i, tm);
      float scl = exp2a((m_i - mnew) * L2E);
      l_p *= scl;
      m_i = mnew;
      float sr0 = __shfl(scl, 4 * l4 + 0);
      float sr1 = __shfl(scl, 4 * l4 + 1);
      float sr2 = __shfl(scl, 4 * l4 + 2);
      float sr3 = __shfl(scl, 4 * l4 + 3);
#pragma unroll
      for (int jd = 0; jd < 4; ++jd) {
        accO[jd][0] *= sr0; accO[jd][1] *= sr1;
        accO[jd][2] *= sr2; accO[jd][3] *= sr3;
      }
    }

    // ---- exp (exp2-folded) + pack f16 + 4x b64 P writes ----
    float ml2 = m_i * L2E;
#pragma unroll
    for (int j = 0; j < 4; ++j) {
      float p0 = exp2a(fmaf(sj[j][0], L2E, -ml2));
      float p1 = exp2a(fmaf(sj[j][1], L2E, -ml2));
      float p2 = exp2a(fmaf(sj[j][2], L2E, -ml2));
      float p3 = exp2a(fmaf(sj[j][3], L2E, -ml2));
      l_p += (p0 + p1) + (p2 + p3);
      unsigned d0, d1;
      asm("v_cvt_pkrtz_f16_f32 %0, %1, %2" : "=v"(d0) : "v"(p0), "v"(p1));
      asm("v_cvt_pkrtz_f16_f32 %0, %1, %2" : "=v"(d1) : "v"(p2), "v"(p3));
      int chunk = ((j << 1) | bhalf) ^ rr7;
      *(u64*)(Pw + prowb + (chunk << 4) + wsub) = (u64)d0 | ((u64)d1 << 32);
    }
    // in-wave ordering: P writes land before A-frag reads
    asm volatile("s_waitcnt lgkmcnt(0)" ::: "memory");
    __builtin_amdgcn_sched_barrier(0);

    // ---- PV ----
    __builtin_amdgcn_s_setprio(1);
#pragma unroll
    for (int kc = 0; kc < 2; ++kc) {
      int chR = (4 * kc + l4) ^ rr7;
      short8 pa = *(const short8*)(Pw + prowb + (chR << 4));
#pragma unroll
      for (int jd = 0; jd < 4; ++jd) {
        short8 vb = *(const short8*)(VT + swz(l15 + 16 * jd, l4 * 16 + 64 * kc));
        accO[jd] = __builtin_amdgcn_mfma_f32_16x16x32_f16(pa, vb, accO[jd], 0, 0, 0);
      }
    }
    __builtin_amdgcn_s_setprio(0);
    __syncthreads();
    cur ^= 1;
  }

  // epilogue: reduce partial l across l4 groups, redistribute to accO rows
  float lr = l_p;
  lr += __shfl_xor(lr, 16);
  lr += __shfl_xor(lr, 32);
  float inv0 = 1.f / __shfl(lr, 4 * l4 + 0);
  float inv1 = 1.f / __shfl(lr, 4 * l4 + 1);
  float inv2 = 1.f / __shfl(lr, 4 * l4 + 2);
  float inv3 = 1.f / __shfl(lr, 4 * l4 + 3);
  float invs[4] = {inv0, inv1, inv2, inv3};
#pragma unroll
  for (int i = 0; i < 4; ++i) {
    int row = q0 + 16 * w + l4 * 4 + i;
    size_t obase = ((size_t)b * S_ + row) * D_ + h * 64 + l15;
#pragma unroll
    for (int jd = 0; jd < 4; ++jd) xout[obase + 16 * jd] = f2h(accO[jd][i] * invs[i]);
  }
}

extern "C" void kernel_launch(void* const* d_in, const int* in_sizes, int n_in,
                              void* d_out, int out_size, void* d_ws, size_t ws_size,
                              hipStream_t stream) {
  const float* q = (const float*)d_in[0];
  const float* k = (const float*)d_in[1];
  const float* v = (const float*)d_in[2];
  const void* mask = d_in[3];
  const float* wq_w = (const float*)d_in[4];
  const float* wq_b = (const float*)d_in[5];
  const float* wk_w = (const float*)d_in[6];
  const float* wk_b = (const float*)d_in[7];
  const float* wv_w = (const float*)d_in[8];
  const float* wv_b = (const float*)d_in[9];
  const float* wo_w = (const float*)d_in[10];
  const float* wo_b = (const float*)d_in[11];

  const size_t NE = (size_t)B_ * S_ * D_;  // 8M elems
  const size_t NW = (size_t)D_ * D_;       // 1M elems
  const size_t PKB = (size_t)(B_ * S_ * (S_ / 32)) * 4;  // 2MB
  char* ws = (char*)d_ws;
  int* flag = (int*)ws;
  unsigned* pkb = (unsigned*)(ws + 256);
  us* base = (us*)(ws + 256 + PKB);

  detect_mask_kernel<<<1, 64, 0, stream>>>((const int*)mask, flag);
  pack_mask<<<2048, 256, 0, stream>>>(mask, flag, pkb);

  dim3 g2(64, 8, 2);
  dim3 g3(64, 8, 3);
  dim3 g1(64, 8, 1);

  const size_t fused_need = 256 + PKB + 6 * NE * 2 + 4 * NW * 2;
  if (ws_size >= fused_need) {
    us* A0 = base;          // q f16 -> later vt
    us* A1 = A0 + NE;       // k f16 -> later xo
    us* A2 = A1 + NE;       // v f16
    us* A3 = A2 + NE;       // qh
    us* A4 = A3 + NE;       // kh
    us* A5 = A4 + NE;       // vh
    us* W0 = A5 + NE;
    us* W1 = W0 + NW;
    us* W2 = W1 + NW;
    us* W3 = W2 + NW;
    cvt_w4<<<2048, 256, 0, stream>>>(wq_w, wk_w, wv_w, wo_w, W0, W1, W2, W3);
    cvt_f16x3<<<3 * 4096, 256, 0, stream>>>(q, k, v, A0, A1, A2);
    gemm_mfma<2><<<g3, 256, 0, stream>>>(A0, A1, A2, W0, W1, W2, wq_b, wk_b, wv_b,
                                         A3, A4, A5, B_ * S_, D_, D_);
    transpose_v<<<2048, 256, 0, stream>>>(A5, A0);  // vt in A0
    attn_mfma<<<1024, 512, 0, stream>>>(A3, A4, A0, pkb, A1);  // xo in A1
    gemm_mfma<0><<<g1, 256, 0, stream>>>(A1, A1, A1, W3, W3, W3, wo_b, wo_b, wo_b,
                                         d_out, d_out, d_out, B_ * S_, D_, D_);
  } else {
    // sequential 5-buffer plan (90.25 MiB)
    us* A0 = base;
    us* A1 = A0 + NE;
    us* A2 = A1 + NE;  // qh
    us* A3 = A2 + NE;  // kh
    us* A4 = A3 + NE;  // vt
    us* W0 = A4 + NE;
    us* W1 = W0 + NW;
    us* W2 = W1 + NW;
    us* W3 = W2 + NW;
    cvt_w4<<<2048, 256, 0, stream>>>(wq_w, wk_w, wv_w, wo_w, W0, W1, W2, W3);
    cvt_f16x3<<<2 * 4096, 256, 0, stream>>>(q, k, nullptr, A0, A1, nullptr);
    gemm_mfma<2><<<g2, 256, 0, stream>>>(A0, A1, nullptr, W0, W1, nullptr, wq_b, wk_b, nullptr,
                                         A2, A3, nullptr, B_ * S_, D_, D_);
    cvt_f16x3<<<4096, 256, 0, stream>>>(v, nullptr, nullptr, A0, nullptr, nullptr);
    gemm_mfma<2><<<g1, 256, 0, stream>>>(A0, nullptr, nullptr, W2, nullptr, nullptr,
                                         wv_b, nullptr, nullptr, A1, nullptr, nullptr,
                                         B_ * S_, D_, D_);
    transpose_v<<<2048, 256, 0, stream>>>(A1, A4);
    attn_mfma<<<1024, 512, 0, stream>>>(A2, A3, A4, pkb, A0);  // xo in A0
    gemm_mfma<0><<<g1, 256, 0, stream>>>(A0, nullptr, nullptr, W3, nullptr, nullptr,
                                         wo_b, nullptr, nullptr, d_out, nullptr, nullptr,
                                         B_ * S_, D_, D_);
  }
}

// Round 9
// 346.600 us; speedup vs baseline: 25.6080x; 1.0506x over previous
//
#include <hip/hip_runtime.h>
#include <hip/hip_bf16.h>

#define B_ 4
#define S_ 2048
#define D_ 1024
#define H_ 16
#define NEGV (-100000.0f)
#define L2E 1.4426950408889634f

typedef __attribute__((ext_vector_type(8))) short short8;
typedef __attribute__((ext_vector_type(4))) float f32x4;
typedef _Float16 hf2 __attribute__((ext_vector_type(2)));
typedef unsigned short us;
typedef unsigned long long u64;

// f32 -> f16 RTNE
__device__ __forceinline__ us f2h(float f) {
  union { _Float16 h; us u; } c;
  c.h = (_Float16)f;
  return c.u;
}
__device__ __forceinline__ float exp2a(float x) {
  float r;
  asm("v_exp_f32 %0, %1" : "=v"(r) : "v"(x));
  return r;
}

// ---------------- mask dtype detection --------------------------------------
__global__ void detect_mask_kernel(const int* __restrict__ mi, int* __restrict__ flag) {
  int t = threadIdx.x;
  bool bad = false;
  for (int i = t; i < 16384; i += 64) {
    int v = mi[i];
    bad = bad || (v != 0 && v != 1);
  }
  unsigned long long any = __ballot(bad);
  if (t == 0) flag[0] = (any != 0ull) ? 1 : 0;  // 1 => byte mask, 0 => int32 mask
}

// ---------------- bit-pack the mask (both dtypes) ---------------------------
__global__ __launch_bounds__(256) void pack_mask(const void* __restrict__ maskp,
                                                 const int* __restrict__ flag,
                                                 unsigned* __restrict__ pk) {
  int w = blockIdx.x * 256 + threadIdx.x;  // word index over B*S*S/32
  unsigned bits = 0;
  if (flag[0]) {
    const uint4* p = (const uint4*)((const unsigned char*)maskp + (size_t)w * 32);
#pragma unroll
    for (int q = 0; q < 2; ++q) {
      uint4 v = p[q];
      unsigned vv[4] = {v.x, v.y, v.z, v.w};
#pragma unroll
      for (int e = 0; e < 4; ++e) {
        unsigned byte4 = vv[e];
#pragma unroll
        for (int bb = 0; bb < 4; ++bb)
          bits |= (unsigned)(((byte4 >> (8 * bb)) & 0xffu) != 0) << (q * 16 + e * 4 + bb);
      }
    }
  } else {
    const uint4* p = (const uint4*)((const int*)maskp + (size_t)w * 32);
#pragma unroll
    for (int q = 0; q < 8; ++q) {
      uint4 v = p[q];
      bits |= (unsigned)(v.x != 0) << (q * 4 + 0);
      bits |= (unsigned)(v.y != 0) << (q * 4 + 1);
      bits |= (unsigned)(v.z != 0) << (q * 4 + 2);
      bits |= (unsigned)(v.w != 0) << (q * 4 + 3);
    }
  }
  pk[w] = bits;
}

// ---------------- f32 -> f16 converts (up to 3 tensors in one launch) -------
__global__ __launch_bounds__(256) void cvt_f16x3(const float* __restrict__ i0,
                                                 const float* __restrict__ i1,
                                                 const float* __restrict__ i2,
                                                 us* __restrict__ o0, us* __restrict__ o1,
                                                 us* __restrict__ o2) {
  int z = blockIdx.x >> 12;  // 4096 blocks per tensor
  int i = (blockIdx.x & 4095) * 256 + threadIdx.x;
  const float* in = z == 0 ? i0 : z == 1 ? i1 : i2;
  us* out = z == 0 ? o0 : z == 1 ? o1 : o2;
  float4 a = ((const float4*)in)[2 * i];
  float4 b = ((const float4*)in)[2 * i + 1];
  us u[8] = {f2h(a.x), f2h(a.y), f2h(a.z), f2h(a.w),
             f2h(b.x), f2h(b.y), f2h(b.z), f2h(b.w)};
  ((uint4*)out)[i] = *(uint4*)u;
}

__global__ __launch_bounds__(256) void cvt_w4(const float* __restrict__ w0,
                                              const float* __restrict__ w1,
                                              const float* __restrict__ w2,
                                              const float* __restrict__ w3,
                                              us* __restrict__ d0, us* __restrict__ d1,
                                              us* __restrict__ d2, us* __restrict__ d3) {
  int which = blockIdx.x >> 9;  // 512 blocks per weight
  int i = (blockIdx.x & 511) * 256 + threadIdx.x;
  const float* w = which == 0 ? w0 : which == 1 ? w1 : which == 2 ? w2 : w3;
  us* d = which == 0 ? d0 : which == 1 ? d1 : which == 2 ? d2 : d3;
  float4 a = ((const float4*)w)[2 * i];
  float4 b = ((const float4*)w)[2 * i + 1];
  us u[8] = {f2h(a.x), f2h(a.y), f2h(a.z), f2h(a.w),
             f2h(b.x), f2h(b.y), f2h(b.z), f2h(b.w)};
  ((uint4*)d)[i] = *(uint4*)u;
}

__device__ __forceinline__ void gload16(const us* g, us* l) {
  __builtin_amdgcn_global_load_lds((const __attribute__((address_space(1))) void*)g,
                                   (__attribute__((address_space(3))) void*)l, 16, 0, 0);
}

// ---------------- MFMA GEMM (fp16): C = A * W^T + bias, up to 3 per launch --
// OMODE 0: fp32 [M][N].  OMODE 2: fp16 head-split [b][h][s][64];
//   if z == trans_z the epilogue instead writes V^T layout [bh][d][S].
__device__ __forceinline__ int swzb(int row, int c16) {  // [128][64] f16 tile, XOR swz
  return row * 128 + ((c16 ^ (row & 7)) << 4);
}

template <int OMODE>
__global__ __launch_bounds__(256) void gemm_mfma(
    const us* __restrict__ A0, const us* __restrict__ A1, const us* __restrict__ A2,
    const us* __restrict__ Wp0, const us* __restrict__ Wp1, const us* __restrict__ Wp2,
    const float* __restrict__ b0, const float* __restrict__ b1, const float* __restrict__ b2,
    void* __restrict__ C0, void* __restrict__ C1, void* __restrict__ C2,
    int M, int N, int K, int trans_z) {
  __shared__ __align__(16) us SM[32768];  // As: [bb*8192], Ws: 16384+[bb*8192]

  const int z = blockIdx.z;
  const us* A = z == 0 ? A0 : z == 1 ? A1 : A2;
  const us* W = z == 0 ? Wp0 : z == 1 ? Wp1 : Wp2;
  const float* bias = z == 0 ? b0 : z == 1 ? b1 : b2;
  void* Cp = z == 0 ? C0 : z == 1 ? C1 : C2;

  const int m0 = blockIdx.x * 128;
  const int n0 = blockIdx.y * 128;
  const int t = threadIdx.x;
  const int w = t >> 6, l = t & 63;
  const int l15 = l & 15, l4 = l >> 4;
  const int wm = w >> 1, wn = w & 1;

  int goff[4];
#pragma unroll
  for (int j = 0; j < 4; ++j) {
    int u = t + j * 256;
    int r = u >> 3, c8 = u & 7;
    int g = c8 ^ (r & 7);  // XOR involution: linear LDS dest, pre-swizzled src
    goff[j] = r * K + g * 8;
  }
  const us* Ag = A + (size_t)m0 * K;
  const us* Wg = W + (size_t)n0 * K;

  f32x4 acc[4][4];
#pragma unroll
  for (int m = 0; m < 4; ++m)
#pragma unroll
    for (int n = 0; n < 4; ++n) acc[m][n] = (f32x4){0.f, 0.f, 0.f, 0.f};

  auto stage = [&](int k0, int bb) {
#pragma unroll
    for (int j = 0; j < 4; ++j) {
      int u = t + j * 256;
      gload16(Ag + goff[j] + k0, SM + bb * 8192 + u * 8);
      gload16(Wg + goff[j] + k0, SM + 16384 + bb * 8192 + u * 8);
    }
  };

  stage(0, 0);
  __syncthreads();
  int cur = 0;
  for (int k0 = 0; k0 < K; k0 += 64) {
    if (k0 + 64 < K) stage(k0 + 64, cur ^ 1);
#pragma unroll
    for (int ks = 0; ks < 2; ++ks) {
      short8 ah[4], bh_[4];
#pragma unroll
      for (int m = 0; m < 4; ++m)
        ah[m] = *(const short8*)((const char*)(SM + cur * 8192) +
                                 swzb(wm * 64 + m * 16 + l15, ks * 4 + l4));
#pragma unroll
      for (int n = 0; n < 4; ++n)
        bh_[n] = *(const short8*)((const char*)(SM + 16384 + cur * 8192) +
                                  swzb(wn * 64 + n * 16 + l15, ks * 4 + l4));
#pragma unroll
      for (int m = 0; m < 4; ++m)
#pragma unroll
        for (int n = 0; n < 4; ++n)
          acc[m][n] = __builtin_amdgcn_mfma_f32_16x16x32_f16(ah[m], bh_[n], acc[m][n], 0, 0, 0);
    }
    __syncthreads();
    cur ^= 1;
  }

  float bv[4];
#pragma unroll
  for (int n = 0; n < 4; ++n) bv[n] = bias[n0 + wn * 64 + n * 16 + l15];

  if (OMODE == 2 && z == trans_z) {
    // ---- transposed epilogue: write V^T [bh][d][S] via LDS [128 col][136 s] ----
    us* T = SM;
#pragma unroll
    for (int n = 0; n < 4; ++n) {
      int col = wn * 64 + n * 16 + l15;
#pragma unroll
      for (int m = 0; m < 4; ++m) {
        int sr = wm * 64 + m * 16 + l4 * 4;
#pragma unroll
        for (int ip = 0; ip < 2; ++ip) {
          us h0 = f2h(acc[m][n][2 * ip] + bv[n]);
          us h1 = f2h(acc[m][n][2 * ip + 1] + bv[n]);
          *(unsigned*)&T[col * 136 + sr + 2 * ip] = (unsigned)h0 | ((unsigned)h1 << 16);
        }
      }
    }
    __syncthreads();
    const int b = m0 >> 11, sb = m0 & (S_ - 1);
    const int colr = t >> 1, sc = (t & 1) << 6;
    const int hh = (n0 >> 6) + (colr >> 6), d = colr & 63;
    us* dst = (us*)Cp + (((size_t)(b * H_ + hh) << 6) + (size_t)d) * S_ + sb + sc;
#pragma unroll
    for (int p = 0; p < 8; ++p)
      *(uint4*)(dst + p * 8) = *(const uint4*)&T[colr * 136 + sc + p * 8];
    return;
  }

#pragma unroll
  for (int m = 0; m < 4; ++m) {
#pragma unroll
    for (int i = 0; i < 4; ++i) {
      int gm = m0 + wm * 64 + m * 16 + l4 * 4 + i;
#pragma unroll
      for (int n = 0; n < 4; ++n) {
        int gn = n0 + wn * 64 + n * 16 + l15;
        float o = acc[m][n][i] + bv[n];
        if constexpr (OMODE == 0) {
          ((float*)Cp)[(size_t)gm * N + gn] = o;
        } else {
          int b = gm >> 11, s = gm & (S_ - 1);
          int hh = gn >> 6, d = gn & 63;
          size_t idx = (((size_t)(b * H_ + hh) << 11) + s) * 64 + d;
          ((us*)Cp)[idx] = f2h(o);
        }
      }
    }
  }
}

// ---------------- MFMA flash attention (fp16, swapped-S^T, 2-phase) ---------
// S^T = mfma(K, Q): lane owns one query (l15), 16 keys. LUT mask, max3 tree,
// packed-f16 l-sum, defer-max, deferred row-sum, XCD swizzle.
__device__ __forceinline__ int swz(int row, int bc) {  // [64][64] f16 tile, XOR swz
  return (row << 7) + (bc ^ ((row & 7) << 4));
}

__global__ __launch_bounds__(512) void attn_mfma(
    const us* __restrict__ qh, const us* __restrict__ kh,
    const us* __restrict__ vt, const unsigned* __restrict__ pk,
    us* __restrict__ xout) {
  __shared__ __align__(16) us Ks[2][4096];  // [64 k][64 d] f16, XOR-swizzled
  __shared__ __align__(16) us Vs[2][4096];  // [64 d][64 k]
  __shared__ __align__(16) char Ps[16384];  // [128 q][64 k] f16 (wave-private rows)
  __shared__ __align__(16) float MLutF[64]; // nibble -> f32x4 additive mask

  const int blk = ((blockIdx.x & 7) << 7) + (blockIdx.x >> 3);  // XCD swizzle
  const int bh = blk >> 4;
  const int q0 = (blk & 15) << 7;
  const int b = bh >> 4, h = bh & (H_ - 1);
  const int t = threadIdx.x;
  const int w = t >> 6, l = t & 63;
  const int l15 = l & 15, l4 = l >> 4;

  short8 qf[2];
  {
    const size_t qbase = ((size_t)bh * S_ + q0 + 16 * w + l15) * 64 + l4 * 8;
    qf[0] = *(const short8*)(qh + qbase);
    qf[1] = *(const short8*)(qh + qbase + 32);
  }

  f32x4 accO[4];
#pragma unroll
  for (int jd = 0; jd < 4; ++jd) accO[jd] = (f32x4){0.f, 0.f, 0.f, 0.f};
  float m_i = -1e30f, l_p = 0.f;  // per-lane: query l15's running max / partial sum

  const int r_st = t >> 3, c_st = (t & 7) ^ ((t >> 3) & 7);
  const us* kh_src = kh + ((size_t)bh * S_ + r_st) * 64 + c_st * 8;
  const us* vt_src = vt + ((size_t)bh * 64 + r_st) * S_ + c_st * 8;

  auto stage = [&](int k0, int bb) {
    gload16(kh_src + (size_t)k0 * 64, &Ks[bb][t * 8]);
    gload16(vt_src + k0, &Vs[bb][t * 8]);
  };

  if (t < 64) MLutF[t] = (((t >> 2) >> (t & 3)) & 1) ? NEGV : 0.f;
  stage(0, 0);
  __syncthreads();
  int cur = 0;

  char* Pw = Ps + w * 2048;     // wave-private 16 rows
  const int prowb = l15 * 128;  // row byte offset
  const int rr7 = l15 & 7;
  const int bhalf = l4 >> 1;
  const int wsub = (l4 & 1) * 8;
  const unsigned* pb = pk + ((size_t)b * S_ + q0 + 16 * w + l15) * (S_ / 32);

  for (int k0 = 0; k0 < S_; k0 += 64) {
    uint2 mw = *(const uint2*)(pb + (k0 >> 5));
    if (k0 + 64 < S_) stage(k0 + 64, cur ^ 1);

    const char* KT = (const char*)Ks[cur];
    const char* VT = (const char*)Vs[cur];

    // ---- S^T = K · Q^T : lane holds S[key = 16j+4*l4+i][q = l15] ----
    __builtin_amdgcn_s_setprio(1);
    f32x4 sj[4];
#pragma unroll
    for (int j = 0; j < 4; ++j) {
      f32x4 s = {0.f, 0.f, 0.f, 0.f};
#pragma unroll
      for (int c = 0; c < 2; ++c) {
        short8 kf = *(const short8*)(KT + swz(l15 + 16 * j, l4 * 16 + 64 * c));
        s = __builtin_amdgcn_mfma_f32_16x16x32_f16(kf, qf[c], s, 0, 0, 0);
      }
      sj[j] = s;
    }
    __builtin_amdgcn_s_setprio(0);

    // ---- mask via f32x4 LDS LUT (nibble-indexed additive {0, NEG}) ----
#pragma unroll
    for (int j = 0; j < 4; ++j) {
      unsigned wrd = (j < 2) ? mw.x : mw.y;
      unsigned nib = (wrd >> (((j & 1) << 4) + (l4 << 2))) & 0xFu;
      f32x4 lv = *(const f32x4*)&MLutF[nib << 2];
      sj[j] = sj[j] + lv;
    }

    // ---- lane-local max (max3-friendly nesting) + 2 shuffles ----
    float c0 = fmaxf(fmaxf(sj[0][0], sj[0][1]), sj[0][2]);
    float c1 = fmaxf(fmaxf(sj[0][3], sj[1][0]), sj[1][1]);
    float c2 = fmaxf(fmaxf(sj[1][2], sj[1][3]), sj[2][0]);
    float c3 = fmaxf(fmaxf(sj[2][1], sj[2][2]), sj[2][3]);
    float c4 = fmaxf(fmaxf(sj[3][0], sj[3][1]), sj[3][2]);
    float tm = fmaxf(fmaxf(fmaxf(c0, c1), c2), fmaxf(fmaxf(c3, c4), sj[3][3]));
    tm = fmaxf(tm, __shfl_xor(tm, 16));
    tm = fmaxf(tm, __shfl_xor(tm, 32));

    // ---- defer-max rescale (rare, wave-uniform) ----
    if (__any(tm - m_i > 8.0f)) {
      float mnew = fmaxf(m_i, tm);
      float scl = exp2a((m_i - mnew) * L2E);
      l_p *= scl;
      m_i = mnew;
      float sr0 = __shfl(scl, 4 * l4 + 0);
      float sr1 = __shfl(scl, 4 * l4 + 1);
      float sr2 = __shfl(scl, 4 * l4 + 2);
      float sr3 = __shfl(scl, 4 * l4 + 3);
#pragma unroll
      for (int jd = 0; jd < 4; ++jd) {
        accO[jd][0] *= sr0; accO[jd][1] *= sr1;
        accO[jd][2] *= sr2; accO[jd][3] *= sr3;
      }
    }

    // ---- exp (exp2-folded, f32) + pack f16 + 4x b64 P writes + pk l-sum ----
    float ml2 = m_i * L2E;
    hf2 acc2;
    acc2.x = (_Float16)0.f;
    acc2.y = (_Float16)0.f;
#pragma unroll
    for (int j = 0; j < 4; ++j) {
      float p0 = exp2a(fmaf(sj[j][0], L2E, -ml2));
      float p1 = exp2a(fmaf(sj[j][1], L2E, -ml2));
      float p2 = exp2a(fmaf(sj[j][2], L2E, -ml2));
      float p3 = exp2a(fmaf(sj[j][3], L2E, -ml2));
      unsigned d0, d1;
      asm("v_cvt_pkrtz_f16_f32 %0, %1, %2" : "=v"(d0) : "v"(p0), "v"(p1));
      asm("v_cvt_pkrtz_f16_f32 %0, %1, %2" : "=v"(d1) : "v"(p2), "v"(p3));
      union { unsigned u; hf2 h; } c0u, c1u;
      c0u.u = d0;
      c1u.u = d1;
      acc2 = acc2 + c0u.h + c1u.h;
      int chunk = ((j << 1) | bhalf) ^ rr7;
      *(u64*)(Pw + prowb + (chunk << 4) + wsub) = (u64)d0 | ((u64)d1 << 32);
    }
    l_p += (float)acc2.x + (float)acc2.y;
    // in-wave ordering: P writes land before A-frag reads
    asm volatile("s_waitcnt lgkmcnt(0)" ::: "memory");
    __builtin_amdgcn_sched_barrier(0);

    // ---- PV ----
    __builtin_amdgcn_s_setprio(1);
#pragma unroll
    for (int kc = 0; kc < 2; ++kc) {
      int chR = (4 * kc + l4) ^ rr7;
      short8 pa = *(const short8*)(Pw + prowb + (chR << 4));
#pragma unroll
      for (int jd = 0; jd < 4; ++jd) {
        short8 vb = *(const short8*)(VT + swz(l15 + 16 * jd, l4 * 16 + 64 * kc));
        accO[jd] = __builtin_amdgcn_mfma_f32_16x16x32_f16(pa, vb, accO[jd], 0, 0, 0);
      }
    }
    __builtin_amdgcn_s_setprio(0);
    __syncthreads();
    cur ^= 1;
  }

  // epilogue: reduce partial l across l4 groups, redistribute to accO rows
  float lr = l_p;
  lr += __shfl_xor(lr, 16);
  lr += __shfl_xor(lr, 32);
  float inv0 = 1.f / __shfl(lr, 4 * l4 + 0);
  float inv1 = 1.f / __shfl(lr, 4 * l4 + 1);
  float inv2 = 1.f / __shfl(lr, 4 * l4 + 2);
  float inv3 = 1.f / __shfl(lr, 4 * l4 + 3);
  float invs[4] = {inv0, inv1, inv2, inv3};
#pragma unroll
  for (int i = 0; i < 4; ++i) {
    int row = q0 + 16 * w + l4 * 4 + i;
    size_t obase = ((size_t)b * S_ + row) * D_ + h * 64 + l15;
#pragma unroll
    for (int jd = 0; jd < 4; ++jd) xout[obase + 16 * jd] = f2h(accO[jd][i] * invs[i]);
  }
}

extern "C" void kernel_launch(void* const* d_in, const int* in_sizes, int n_in,
                              void* d_out, int out_size, void* d_ws, size_t ws_size,
                              hipStream_t stream) {
  const float* q = (const float*)d_in[0];
  const float* k = (const float*)d_in[1];
  const float* v = (const float*)d_in[2];
  const void* mask = d_in[3];
  const float* wq_w = (const float*)d_in[4];
  const float* wq_b = (const float*)d_in[5];
  const float* wk_w = (const float*)d_in[6];
  const float* wk_b = (const float*)d_in[7];
  const float* wv_w = (const float*)d_in[8];
  const float* wv_b = (const float*)d_in[9];
  const float* wo_w = (const float*)d_in[10];
  const float* wo_b = (const float*)d_in[11];

  const size_t NE = (size_t)B_ * S_ * D_;  // 8M elems
  const size_t NW = (size_t)D_ * D_;       // 1M elems
  const size_t PKB = (size_t)(B_ * S_ * (S_ / 32)) * 4;  // 2MB
  char* ws = (char*)d_ws;
  int* flag = (int*)ws;
  unsigned* pkb = (unsigned*)(ws + 256);
  us* base = (us*)(ws + 256 + PKB);

  detect_mask_kernel<<<1, 64, 0, stream>>>((const int*)mask, flag);
  pack_mask<<<2048, 256, 0, stream>>>(mask, flag, pkb);

  dim3 g2(64, 8, 2);
  dim3 g3(64, 8, 3);
  dim3 g1(64, 8, 1);

  const size_t fused_need = 256 + PKB + 6 * NE * 2 + 4 * NW * 2;
  if (ws_size >= fused_need) {
    us* A0 = base;          // q f16 -> later xo
    us* A1 = A0 + NE;       // k f16
    us* A2 = A1 + NE;       // v f16
    us* A3 = A2 + NE;       // qh
    us* A4 = A3 + NE;       // kh
    us* A5 = A4 + NE;       // vt
    us* W0 = A5 + NE;
    us* W1 = W0 + NW;
    us* W2 = W1 + NW;
    us* W3 = W2 + NW;
    cvt_w4<<<2048, 256, 0, stream>>>(wq_w, wk_w, wv_w, wo_w, W0, W1, W2, W3);
    cvt_f16x3<<<3 * 4096, 256, 0, stream>>>(q, k, v, A0, A1, A2);
    gemm_mfma<2><<<g3, 256, 0, stream>>>(A0, A1, A2, W0, W1, W2, wq_b, wk_b, wv_b,
                                         A3, A4, A5, B_ * S_, D_, D_, 2);
    attn_mfma<<<1024, 512, 0, stream>>>(A3, A4, A5, pkb, A0);  // xo in A0
    gemm_mfma<0><<<g1, 256, 0, stream>>>(A0, A0, A0, W3, W3, W3, wo_b, wo_b, wo_b,
                                         d_out, d_out, d_out, B_ * S_, D_, D_, -1);
  } else {
    // sequential 5-buffer plan
    us* A0 = base;
    us* A1 = A0 + NE;
    us* A2 = A1 + NE;  // qh
    us* A3 = A2 + NE;  // kh
    us* A4 = A3 + NE;  // vt
    us* W0 = A4 + NE;
    us* W1 = W0 + NW;
    us* W2 = W1 + NW;
    us* W3 = W2 + NW;
    cvt_w4<<<2048, 256, 0, stream>>>(wq_w, wk_w, wv_w, wo_w, W0, W1, W2, W3);
    cvt_f16x3<<<2 * 4096, 256, 0, stream>>>(q, k, nullptr, A0, A1, nullptr);
    gemm_mfma<2><<<g2, 256, 0, stream>>>(A0, A1, nullptr, W0, W1, nullptr, wq_b, wk_b, nullptr,
                                         A2, A3, nullptr, B_ * S_, D_, D_, -1);
    cvt_f16x3<<<4096, 256, 0, stream>>>(v, nullptr, nullptr, A0, nullptr, nullptr);
    gemm_mfma<2><<<g1, 256, 0, stream>>>(A0, nullptr, nullptr, W2, nullptr, nullptr,
                                         wv_b, nullptr, nullptr, A4, nullptr, nullptr,
                                         B_ * S_, D_, D_, 0);  // V -> vt (transposed)
    attn_mfma<<<1024, 512, 0, stream>>>(A2, A3, A4, pkb, A0);  // xo in A0
    gemm_mfma<0><<<g1, 256, 0, stream>>>(A0, nullptr, nullptr, W3, nullptr, nullptr,
                                         wo_b, nullptr, nullptr, d_out, nullptr, nullptr,
                                         B_ * S_, D_, D_, -1);
  }
}